// Round 4
// baseline (2438.237 us; speedup 1.0000x reference)
//
#include <hip/hip_runtime.h>
#include <hip/hip_bf16.h>
#include <math.h>

#define D_MODEL 768
#define T_SEQ   1024
#define B_BATCH 16
#define MLP_DIM 3072
#define M_ROWS  (B_BATCH * T_SEQ)   // 16384

typedef __attribute__((ext_vector_type(8))) __bf16          bf16x8;
typedef __attribute__((ext_vector_type(8))) unsigned short  ushort8;
typedef __attribute__((ext_vector_type(4))) float           f32x4;

__device__ __forceinline__ float bf2f(unsigned short u) {
  union { unsigned int u; float f; } w; w.u = ((unsigned int)u) << 16; return w.f;
}
__device__ __forceinline__ unsigned short f2bf(float f) {
  union { float f; unsigned int u; } w; w.f = f;
  unsigned int r = (w.u + 0x7fffu + ((w.u >> 16) & 1u)) >> 16;
  return (unsigned short)r;
}
__device__ __forceinline__ float gelu_f(float x) {
  return 0.5f * x * (1.0f + erff(x * 0.70710678118654752f));
}

// ---------------- per-row LN stats: (mu, rsqrt(var+eps)) -------------------
// SRC_F32=1: src is float; 0: src is bf16
template<int SRC_F32>
__global__ __launch_bounds__(256) void stats_k(
    const void* __restrict__ src, float2* __restrict__ st) {
  const int row = blockIdx.x, tid = threadIdx.x;
  const size_t base = (size_t)row * D_MODEL;
  float s = 0.f, sq = 0.f;
  #pragma unroll
  for (int i = 0; i < 3; ++i) {
    const int c = tid + (i << 8);
    float v = SRC_F32 ? ((const float*)src)[base + c]
                      : bf2f(((const unsigned short*)src)[base + c]);
    s += v; sq += v * v;
  }
  #pragma unroll
  for (int m = 32; m; m >>= 1) { s += __shfl_xor(s, m); sq += __shfl_xor(sq, m); }
  __shared__ float ps[4], pq[4];
  if ((tid & 63) == 0) { ps[tid >> 6] = s; pq[tid >> 6] = sq; }
  __syncthreads();
  if (tid == 0) {
    s  = ps[0] + ps[1] + ps[2] + ps[3];
    sq = pq[0] + pq[1] + pq[2] + pq[3];
    const float mu  = s * (1.0f / 768.0f);
    const float var = sq * (1.0f / 768.0f) - mu * mu;
    st[row] = make_float2(mu, rsqrtf(var + 1e-5f));
  }
}

// ---- GEMM: C[M,N] = LN?(A[M,K]) @ W[K,N] + bias, fused epilogues ----------
// A: f32 (AF32=1) or bf16 (AF32=0). W, bias, g, bt: f32.
// EP 0: bf16 store            | 1: gelu -> bf16
// EP 2: +resid(f32) -> bf16   | 3: gelu + resid(bf16) -> f32 (final output)
// EP 4: bf16 in V^T layout vt[(row>>10)*768 + col][row&1023]
template<int EP, int LNA, int AF32>
__global__ __launch_bounds__(256) void gemm_k(
    const void* __restrict__ Av, const float* __restrict__ W,
    const float* __restrict__ bias, void* __restrict__ outv,
    const void* __restrict__ residv, const float2* __restrict__ stats,
    const float* __restrict__ g, const float* __restrict__ bt,
    int M, int N, int K) {
  __shared__ __align__(16) unsigned short As[128][40];
  __shared__ __align__(16) unsigned short Bs[128][40];
  const int tid = threadIdx.x;
  const int lane = tid & 63, wid = tid >> 6;
  const int wr = wid >> 1, wc = wid & 1;
  const int brow = blockIdx.x * 128, bcol = blockIdx.y * 128;
  const int lr = lane & 15, lg = lane >> 4;
  f32x4 acc[4][4];
  #pragma unroll
  for (int m = 0; m < 4; ++m)
    #pragma unroll
    for (int n = 0; n < 4; ++n) acc[m][n] = (f32x4){0.f, 0.f, 0.f, 0.f};

  for (int k0 = 0; k0 < K; k0 += 32) {
    __syncthreads();
    // A-tile: rows brow..+128, k-cols k0..+32 (optional fused LayerNorm)
    #pragma unroll
    for (int p = 0; p < 2; ++p) {
      const int idx = p * 256 + tid;
      const int r = idx >> 2, c = (idx & 3) << 3;
      float av[8];
      if (AF32) {
        const float* Ap = (const float*)Av + (size_t)(brow + r) * K + k0 + c;
        const float4 a0 = *(const float4*)Ap, a1 = *(const float4*)(Ap + 4);
        av[0]=a0.x; av[1]=a0.y; av[2]=a0.z; av[3]=a0.w;
        av[4]=a1.x; av[5]=a1.y; av[6]=a1.z; av[7]=a1.w;
      } else {
        const ushort8 u = *(const ushort8*)((const unsigned short*)Av +
                              (size_t)(brow + r) * K + k0 + c);
        #pragma unroll
        for (int j = 0; j < 8; ++j) av[j] = bf2f(u[j]);
      }
      if (LNA) {
        const float2 st = stats[brow + r];
        #pragma unroll
        for (int j = 0; j < 8; ++j)
          av[j] = (av[j] - st.x) * st.y * g[k0 + c + j] + bt[k0 + c + j];
      }
      ushort8 o;
      #pragma unroll
      for (int j = 0; j < 8; ++j) o[j] = f2bf(av[j]);
      *(ushort8*)(&As[r][c]) = o;
    }
    // B-tile: W[k0..+32][bcol..+128] (f32), transposed into Bs[n][kk] as bf16
    #pragma unroll
    for (int p = 0; p < 2; ++p) {
      const int idx = p * 256 + tid;
      const int kk = idx >> 4, n0 = (idx & 15) << 3;
      const float* wp = W + (size_t)(k0 + kk) * N + bcol + n0;
      const float4 w0 = *(const float4*)wp, w1 = *(const float4*)(wp + 4);
      Bs[n0 + 0][kk] = f2bf(w0.x); Bs[n0 + 1][kk] = f2bf(w0.y);
      Bs[n0 + 2][kk] = f2bf(w0.z); Bs[n0 + 3][kk] = f2bf(w0.w);
      Bs[n0 + 4][kk] = f2bf(w1.x); Bs[n0 + 5][kk] = f2bf(w1.y);
      Bs[n0 + 6][kk] = f2bf(w1.z); Bs[n0 + 7][kk] = f2bf(w1.w);
    }
    __syncthreads();
    bf16x8 af[4], bfr[4];
    #pragma unroll
    for (int m = 0; m < 4; ++m) af[m]  = *(const bf16x8*)(&As[wr*64 + m*16 + lr][lg*8]);
    #pragma unroll
    for (int n = 0; n < 4; ++n) bfr[n] = *(const bf16x8*)(&Bs[wc*64 + n*16 + lr][lg*8]);
    #pragma unroll
    for (int m = 0; m < 4; ++m)
      #pragma unroll
      for (int n = 0; n < 4; ++n)
        acc[m][n] = __builtin_amdgcn_mfma_f32_16x16x32_bf16(af[m], bfr[n], acc[m][n], 0, 0, 0);
  }

  #pragma unroll
  for (int n = 0; n < 4; ++n) {
    const int col = bcol + wc*64 + n*16 + lr;
    const float bv = bias[col];
    #pragma unroll
    for (int m = 0; m < 4; ++m) {
      const int row0 = brow + wr*64 + m*16 + lg*4;
      #pragma unroll
      for (int r = 0; r < 4; ++r) {
        const int gr = row0 + r;
        const size_t o = (size_t)gr * N + col;
        float v = acc[m][n][r] + bv;
        if (EP == 0)      ((unsigned short*)outv)[o] = f2bf(v);
        else if (EP == 1) ((unsigned short*)outv)[o] = f2bf(gelu_f(v));
        else if (EP == 2) ((unsigned short*)outv)[o] = f2bf(v + ((const float*)residv)[o]);
        else if (EP == 3) ((float*)outv)[o] = gelu_f(v) + bf2f(((const unsigned short*)residv)[o]);
        else ((unsigned short*)outv)[(((size_t)(gr >> 10) * D_MODEL + col) << 10) + (gr & 1023)] = f2bf(v);
      }
    }
  }
}

// ---------------- fused attention, IN-PLACE on q: block = (b, h, 16 rows) --
// Reads q rows [q0,q0+16) cols [64h,64h+64) into registers first, writes the
// same region last; regions are disjoint across blocks -> in-place is safe.
__global__ __launch_bounds__(256) void attn_k(
    const unsigned short* q, const unsigned short* __restrict__ k,
    const unsigned short* __restrict__ vt, unsigned short* attn) {
  __shared__ float S[16][1024];            // 64 KB
  __shared__ unsigned short P[16][1024];   // 32 KB
  const int b = blockIdx.z, h = blockIdx.y, q0 = blockIdx.x * 16;
  const int tid = threadIdx.x, lane = tid & 63, wid = tid >> 6;
  const int lr = lane & 15, lg = lane >> 4;
  const float scale = 0.03608439182435161f; // 1/sqrt(768)

  const size_t qoff = ((size_t)(b * T_SEQ + q0 + lr)) * D_MODEL + h * 64 + lg * 8;
  bf16x8 qa0 = *(const bf16x8*)(q + qoff);
  bf16x8 qa1 = *(const bf16x8*)(q + qoff + 32);

  const unsigned short* kb = k + (size_t)b * T_SEQ * D_MODEL + h * 64;
  for (int jt = wid; jt < 64; jt += 4) {
    const size_t ko = (size_t)(jt * 16 + lr) * D_MODEL + lg * 8;
    bf16x8 k0v = *(const bf16x8*)(kb + ko);
    bf16x8 k1v = *(const bf16x8*)(kb + ko + 32);
    f32x4 a = (f32x4){0.f, 0.f, 0.f, 0.f};
    a = __builtin_amdgcn_mfma_f32_16x16x32_bf16(qa0, k0v, a, 0, 0, 0);
    a = __builtin_amdgcn_mfma_f32_16x16x32_bf16(qa1, k1v, a, 0, 0, 0);
    #pragma unroll
    for (int r = 0; r < 4; ++r) S[lg * 4 + r][jt * 16 + lr] = a[r] * scale;
  }
  __syncthreads();

  {
    const int row = tid >> 4, c = tid & 15;
    float mx = -1e30f;
    #pragma unroll 8
    for (int i = 0; i < 64; ++i) mx = fmaxf(mx, S[row][c + 16 * i]);
    #pragma unroll
    for (int m = 1; m < 16; m <<= 1) mx = fmaxf(mx, __shfl_xor(mx, m));
    float sum = 0.f;
    #pragma unroll 8
    for (int i = 0; i < 64; ++i) {
      float e = expf(S[row][c + 16 * i] - mx);
      S[row][c + 16 * i] = e; sum += e;
    }
    #pragma unroll
    for (int m = 1; m < 16; m <<= 1) sum += __shfl_xor(sum, m);
    const float inv = 1.0f / sum;
    #pragma unroll 8
    for (int i = 0; i < 64; ++i) P[row][c + 16 * i] = f2bf(S[row][c + 16 * i] * inv);
  }
  __syncthreads();

  const unsigned short* vb = vt + ((size_t)b * D_MODEL + h * 64 + wid * 16 + lr) * T_SEQ;
  f32x4 a = (f32x4){0.f, 0.f, 0.f, 0.f};
  #pragma unroll 4
  for (int jt = 0; jt < 32; ++jt) {
    bf16x8 pa = *(const bf16x8*)(&P[lr][jt * 32 + lg * 8]);
    bf16x8 vv = *(const bf16x8*)(vb + jt * 32 + lg * 8);
    a = __builtin_amdgcn_mfma_f32_16x16x32_bf16(pa, vv, a, 0, 0, 0);
  }
  const int ocol = h * 64 + wid * 16 + lr;
  const size_t orow0 = (size_t)b * T_SEQ + q0 + lg * 4;
  #pragma unroll
  for (int r = 0; r < 4; ++r) attn[(orow0 + r) * D_MODEL + ocol] = f2bf(a[r]);
}

// ---------------------------------------------------------------------------
extern "C" void kernel_launch(void* const* d_in, const int* in_sizes, int n_in,
                              void* d_out, int out_size, void* d_ws, size_t ws_size,
                              hipStream_t stream) {
  const float* x   = (const float*)d_in[0];
  const float* Wq  = (const float*)d_in[1];
  const float* bq  = (const float*)d_in[2];
  const float* Wk  = (const float*)d_in[3];
  const float* bk  = (const float*)d_in[4];
  const float* Wv  = (const float*)d_in[5];
  const float* bv  = (const float*)d_in[6];
  const float* Wo  = (const float*)d_in[7];
  const float* bo  = (const float*)d_in[8];
  const float* g1  = (const float*)d_in[9];
  const float* bt1 = (const float*)d_in[10];
  const float* g2  = (const float*)d_in[11];
  const float* bt2 = (const float*)d_in[12];
  const float* W1  = (const float*)d_in[13];
  const float* bb1 = (const float*)d_in[14];
  const float* W2  = (const float*)d_in[15];
  const float* bb2 = (const float*)d_in[16];

  // ws (50,593,792 B total), all intermediates bf16:
  //   slotA @0    : k    -> res2 (attn proj + x)
  //   slotB @SZ   : v^T  -> MLP hidden [4096][3072]
  //   stats @2*SZ : stats1 + stats2 (128KB each)
  // q + attention output live in the front 25MB of d_out (bf16, in-place);
  // dead before the final MLP2 writes f32 over all of d_out.
  const size_t SZ = (size_t)M_ROWS * D_MODEL * 2;  // 25,165,824
  char* ws = (char*)d_ws;
  unsigned short* slotA = (unsigned short*)(ws + 0);
  unsigned short* slotB = (unsigned short*)(ws + 1 * SZ);
  float2* stats1 = (float2*)(ws + 2 * SZ);
  float2* stats2 = stats1 + M_ROWS;
  unsigned short* qd   = (unsigned short*)d_out;
  unsigned short* res2 = slotA;
  unsigned short* hid  = slotB;

  stats_k<1><<<M_ROWS, 256, 0, stream>>>(x, stats1);

  gemm_k<0,1,1><<<dim3(128, 6), 256, 0, stream>>>(x, Wq, bq, qd,    nullptr, stats1, g1, bt1, M_ROWS, 768, 768);
  gemm_k<0,1,1><<<dim3(128, 6), 256, 0, stream>>>(x, Wk, bk, slotA, nullptr, stats1, g1, bt1, M_ROWS, 768, 768);
  gemm_k<4,1,1><<<dim3(128, 6), 256, 0, stream>>>(x, Wv, bv, slotB, nullptr, stats1, g1, bt1, M_ROWS, 768, 768);

  attn_k<<<dim3(64, 12, 16), 256, 0, stream>>>(qd, slotA, slotB, qd);

  gemm_k<2,0,0><<<dim3(128, 6), 256, 0, stream>>>(qd, Wo, bo, res2, x, nullptr, nullptr, nullptr, M_ROWS, 768, 768);

  stats_k<0><<<M_ROWS, 256, 0, stream>>>(res2, stats2);

  for (int c = 0; c < 4; ++c) {
    const size_t ro = (size_t)c * 4096;
    gemm_k<1,1,0><<<dim3(32, 24), 256, 0, stream>>>(res2 + ro * 768, W1, bb1, hid,
        nullptr, stats2 + ro, g2, bt2, 4096, 3072, 768);
    gemm_k<3,0,0><<<dim3(32, 6), 256, 0, stream>>>(hid, W2, bb2,
        (float*)d_out + ro * 768, res2 + ro * 768, nullptr, nullptr, nullptr, 4096, 768, 3072);
  }
}

// Round 6
// 788.325 us; speedup vs baseline: 3.0929x; 3.0929x over previous
//
#include <hip/hip_runtime.h>
#include <hip/hip_bf16.h>
#include <math.h>

#define D_MODEL 768
#define T_SEQ   1024
#define B_BATCH 16
#define MLP_DIM 3072
#define M_ROWS  (B_BATCH * T_SEQ)   // 16384

typedef __attribute__((ext_vector_type(8))) __bf16          bf16x8;
typedef __attribute__((ext_vector_type(4))) __bf16          bf16x4;
typedef __attribute__((ext_vector_type(4))) float           f32x4;

__device__ __forceinline__ float bf2f(unsigned short u) {
  union { unsigned int u; float f; } w; w.u = ((unsigned int)u) << 16; return w.f;
}
__device__ __forceinline__ unsigned short f2bf(float f) {
  union { float f; unsigned int u; } w; w.f = f;
  unsigned int r = (w.u + 0x7fffu + ((w.u >> 16) & 1u)) >> 16;
  return (unsigned short)r;
}
__device__ __forceinline__ float gelu_f(float x) {
  return 0.5f * x * (1.0f + erff(x * 0.70710678118654752f));
}

// ------- weight transpose+convert: dst[N=C][K=R] bf16 = src[R][C] f32 ------
__global__ void wtr_k(const float* __restrict__ src,
                      unsigned short* __restrict__ dst, int R, int C) {
  __shared__ float t[32][33];
  const int c0 = blockIdx.x * 32, r0 = blockIdx.y * 32;
  const int tx = threadIdx.x, ty = threadIdx.y;
  #pragma unroll
  for (int j = 0; j < 32; j += 8)
    t[ty + j][tx] = src[(size_t)(r0 + ty + j) * C + (c0 + tx)];
  __syncthreads();
  #pragma unroll
  for (int j = 0; j < 32; j += 8)
    dst[(size_t)(c0 + ty + j) * R + (r0 + tx)] = f2bf(t[tx][ty + j]);
}

// ---------- fused LayerNorm (stats + apply), one block per row -------------
// SRC_F32: 1 = f32 input, 0 = bf16 input. Output bf16. g/b are f32.
template<int SRC_F32>
__global__ __launch_bounds__(256) void ln_k(const void* __restrict__ src,
    const float* __restrict__ g, const float* __restrict__ b,
    unsigned short* __restrict__ out) {
  const int row = blockIdx.x, tid = threadIdx.x;
  const size_t base = (size_t)row * D_MODEL;
  float v[3];
  #pragma unroll
  for (int i = 0; i < 3; ++i) {
    const int c = tid + (i << 8);
    v[i] = SRC_F32 ? ((const float*)src)[base + c]
                   : bf2f(((const unsigned short*)src)[base + c]);
  }
  float s  = v[0] + v[1] + v[2];
  float sq = v[0]*v[0] + v[1]*v[1] + v[2]*v[2];
  #pragma unroll
  for (int m = 32; m; m >>= 1) { s += __shfl_xor(s, m); sq += __shfl_xor(sq, m); }
  __shared__ float ps[4], pq[4];
  if ((tid & 63) == 0) { ps[tid >> 6] = s; pq[tid >> 6] = sq; }
  __syncthreads();
  s  = ps[0] + ps[1] + ps[2] + ps[3];
  sq = pq[0] + pq[1] + pq[2] + pq[3];
  const float mu  = s * (1.0f / 768.0f);
  const float var = sq * (1.0f / 768.0f) - mu * mu;
  const float inv = rsqrtf(var + 1e-5f);
  #pragma unroll
  for (int i = 0; i < 3; ++i) {
    const int c = tid + (i << 8);
    out[base + c] = f2bf((v[i] - mu) * inv * g[c] + b[c]);
  }
}

// ---- GEMM: C[M,N] = A[M,K](bf16) @ Bt[N,K]^T(bf16) + bias(f32) ------------
// EP 0: bf16 store            | 1: gelu -> bf16
// EP 2: +resid(f32) -> bf16   | 3: gelu + resid(bf16) -> f32 (final output)
// EP 4: bf16 in V^T layout vt[(row>>10)*768 + col][row&1023]
template<int EP>
__global__ __launch_bounds__(256) void gemm_k(
    const unsigned short* __restrict__ Au, const unsigned short* __restrict__ Btu,
    const float* __restrict__ bias, void* __restrict__ outv,
    const void* __restrict__ residv, int M, int N, int K) {
  __shared__ __align__(16) __bf16 As[128][40];
  __shared__ __align__(16) __bf16 Bs[128][40];
  const __bf16* A  = (const __bf16*)Au;
  const __bf16* Bt = (const __bf16*)Btu;
  const int tid = threadIdx.x;
  const int lane = tid & 63, wid = tid >> 6;
  const int wr = wid >> 1, wc = wid & 1;
  const int brow = blockIdx.x * 128, bcol = blockIdx.y * 128;
  const int lr = lane & 15, lg = lane >> 4;
  f32x4 acc[4][4];
  #pragma unroll
  for (int m = 0; m < 4; ++m)
    #pragma unroll
    for (int n = 0; n < 4; ++n) acc[m][n] = (f32x4){0.f, 0.f, 0.f, 0.f};

  for (int k0 = 0; k0 < K; k0 += 32) {
    __syncthreads();
    #pragma unroll
    for (int p = 0; p < 2; ++p) {
      const int idx = p * 256 + tid;
      const int r = idx >> 2, c = (idx & 3) << 3;
      *(bf16x8*)(&As[r][c]) = *(const bf16x8*)(A  + (size_t)(brow + r) * K + k0 + c);
      *(bf16x8*)(&Bs[r][c]) = *(const bf16x8*)(Bt + (size_t)(bcol + r) * K + k0 + c);
    }
    __syncthreads();
    bf16x8 af[4], bfr[4];
    #pragma unroll
    for (int m = 0; m < 4; ++m) af[m]  = *(const bf16x8*)(&As[wr*64 + m*16 + lr][lg*8]);
    #pragma unroll
    for (int n = 0; n < 4; ++n) bfr[n] = *(const bf16x8*)(&Bs[wc*64 + n*16 + lr][lg*8]);
    #pragma unroll
    for (int m = 0; m < 4; ++m)
      #pragma unroll
      for (int n = 0; n < 4; ++n)
        acc[m][n] = __builtin_amdgcn_mfma_f32_16x16x32_bf16(af[m], bfr[n], acc[m][n], 0, 0, 0);
  }

  #pragma unroll
  for (int n = 0; n < 4; ++n) {
    const int col = bcol + wc*64 + n*16 + lr;
    const float bv = bias[col];
    #pragma unroll
    for (int m = 0; m < 4; ++m) {
      const int row0 = brow + wr*64 + m*16 + lg*4;
      #pragma unroll
      for (int r = 0; r < 4; ++r) {
        const int gr = row0 + r;
        const size_t o = (size_t)gr * N + col;
        float v = acc[m][n][r] + bv;
        if (EP == 0)      ((unsigned short*)outv)[o] = f2bf(v);
        else if (EP == 1) ((unsigned short*)outv)[o] = f2bf(gelu_f(v));
        else if (EP == 2) ((unsigned short*)outv)[o] = f2bf(v + ((const float*)residv)[o]);
        else if (EP == 3) ((float*)outv)[o] = gelu_f(v) + bf2f(((const unsigned short*)residv)[o]);
        else ((unsigned short*)outv)[(((size_t)(gr >> 10) * D_MODEL + col) << 10) + (gr & 1023)] = f2bf(v);
      }
    }
  }
}

// ---------------- flash attention: block = (b, h, 64 q-rows), 4 waves ------
// Swapped QK^T (S^T = K·Q^T) -> per-lane row-local softmax; online m/l;
// PV as O^T = V^T·P^T. In-place on q (block reads exactly the region it
// writes; regions disjoint across blocks).
__global__ __launch_bounds__(256) void attn_k(
    const unsigned short* qu, const unsigned short* __restrict__ ku,
    const unsigned short* __restrict__ vtu, unsigned short* attn) {
  __shared__ __align__(16) __bf16 Kl[64][72];
  __shared__ __align__(16) __bf16 Vl[64][72];
  __shared__ __align__(16) __bf16 Pl[4][16][72];
  const __bf16* qg  = (const __bf16*)qu;
  const __bf16* kg  = (const __bf16*)ku;
  const __bf16* vtg = (const __bf16*)vtu;
  const int b = blockIdx.z, h = blockIdx.y, q0 = blockIdx.x * 64;
  const int tid = threadIdx.x, lane = tid & 63, w = tid >> 6;
  const int lr = lane & 15, lg = lane >> 4;
  const float scale = 0.03608439182435161f; // 1/sqrt(768)

  const int qrow = b * T_SEQ + q0 + w * 16 + lr;
  const __bf16* qp = qg + (size_t)qrow * D_MODEL + h * 64 + lg * 8;
  const bf16x8 qa0 = *(const bf16x8*)(qp);
  const bf16x8 qa1 = *(const bf16x8*)(qp + 32);

  const __bf16* kb = kg  + (size_t)b * T_SEQ * D_MODEL + h * 64;
  const __bf16* vb = vtg + ((size_t)b * D_MODEL + h * 64) * T_SEQ;

  f32x4 o[4];
  #pragma unroll
  for (int m = 0; m < 4; ++m) o[m] = (f32x4){0.f, 0.f, 0.f, 0.f};
  float m_run = -1e30f, l_run = 0.f;

  for (int kv0 = 0; kv0 < T_SEQ; kv0 += 64) {
    __syncthreads();
    // stage 64x64 K-tile (row-major) and V^T-tile: 512 slots of 8 bf16
    #pragma unroll
    for (int p = 0; p < 2; ++p) {
      const int idx = p * 256 + tid;
      const int r = idx >> 3, c = (idx & 7) << 3;
      *(bf16x8*)(&Kl[r][c]) = *(const bf16x8*)(kb + (size_t)(kv0 + r) * D_MODEL + c);
      *(bf16x8*)(&Vl[r][c]) = *(const bf16x8*)(vb + (size_t)r * T_SEQ + kv0 + c);
    }
    __syncthreads();

    // QK^T (swapped): s[m] holds S^T[kv = 16m+4lg+r][q = lr]
    f32x4 s[4];
    #pragma unroll
    for (int m = 0; m < 4; ++m) {
      s[m] = (f32x4){0.f, 0.f, 0.f, 0.f};
      const bf16x8 kf0 = *(const bf16x8*)(&Kl[m*16 + lr][lg*8]);
      const bf16x8 kf1 = *(const bf16x8*)(&Kl[m*16 + lr][32 + lg*8]);
      s[m] = __builtin_amdgcn_mfma_f32_16x16x32_bf16(kf0, qa0, s[m], 0, 0, 0);
      s[m] = __builtin_amdgcn_mfma_f32_16x16x32_bf16(kf1, qa1, s[m], 0, 0, 0);
    }
    // online softmax for q = lr (16 values in-lane, reduce across lg)
    float sv[4][4];
    float tm = -1e30f;
    #pragma unroll
    for (int m = 0; m < 4; ++m)
      #pragma unroll
      for (int r = 0; r < 4; ++r) {
        sv[m][r] = s[m][r] * scale;
        tm = fmaxf(tm, sv[m][r]);
      }
    tm = fmaxf(tm, __shfl_xor(tm, 16));
    tm = fmaxf(tm, __shfl_xor(tm, 32));
    const float mn = fmaxf(m_run, tm);
    const float sc = __expf(m_run - mn);
    float ts = 0.f;
    bf16x4 pk[4];
    #pragma unroll
    for (int m = 0; m < 4; ++m)
      #pragma unroll
      for (int r = 0; r < 4; ++r) {
        const float pp = __expf(sv[m][r] - mn);
        ts += pp;
        pk[m][r] = (__bf16)pp;
      }
    ts += __shfl_xor(ts, 16);
    ts += __shfl_xor(ts, 32);
    l_run = l_run * sc + ts;
    m_run = mn;
    #pragma unroll
    for (int m = 0; m < 4; ++m)
      #pragma unroll
      for (int r = 0; r < 4; ++r) o[m][r] *= sc;
    // P bounce through per-wave LDS into B-fragment layout
    #pragma unroll
    for (int m = 0; m < 4; ++m)
      *(bf16x4*)(&Pl[w][lr][16*m + 4*lg]) = pk[m];
    const bf16x8 pf0 = *(const bf16x8*)(&Pl[w][lr][lg*8]);
    const bf16x8 pf1 = *(const bf16x8*)(&Pl[w][lr][32 + lg*8]);
    // PV: O^T[d = 16m+4lg+r][q = lr]
    #pragma unroll
    for (int m = 0; m < 4; ++m) {
      const bf16x8 vf0 = *(const bf16x8*)(&Vl[m*16 + lr][lg*8]);
      const bf16x8 vf1 = *(const bf16x8*)(&Vl[m*16 + lr][32 + lg*8]);
      o[m] = __builtin_amdgcn_mfma_f32_16x16x32_bf16(vf0, pf0, o[m], 0, 0, 0);
      o[m] = __builtin_amdgcn_mfma_f32_16x16x32_bf16(vf1, pf1, o[m], 0, 0, 0);
    }
  }

  const float inv = 1.0f / l_run;
  unsigned short* op = attn + (size_t)qrow * D_MODEL + h * 64;
  #pragma unroll
  for (int m = 0; m < 4; ++m) {
    bf16x4 ov;
    #pragma unroll
    for (int r = 0; r < 4; ++r) ov[r] = (__bf16)(o[m][r] * inv);
    *(bf16x4*)(op + 16*m + 4*lg) = ov;
  }
}

// ---------------------------------------------------------------------------
extern "C" void kernel_launch(void* const* d_in, const int* in_sizes, int n_in,
                              void* d_out, int out_size, void* d_ws, size_t ws_size,
                              hipStream_t stream) {
  const float* x   = (const float*)d_in[0];
  const float* Wq  = (const float*)d_in[1];
  const float* bq  = (const float*)d_in[2];
  const float* Wk  = (const float*)d_in[3];
  const float* bk  = (const float*)d_in[4];
  const float* Wv  = (const float*)d_in[5];
  const float* bv  = (const float*)d_in[6];
  const float* Wo  = (const float*)d_in[7];
  const float* bo  = (const float*)d_in[8];
  const float* g1  = (const float*)d_in[9];
  const float* bt1 = (const float*)d_in[10];
  const float* g2  = (const float*)d_in[11];
  const float* bt2 = (const float*)d_in[12];
  const float* W1  = (const float*)d_in[13];
  const float* bb1 = (const float*)d_in[14];
  const float* W2  = (const float*)d_in[15];
  const float* bb2 = (const float*)d_in[16];

  // d_out (f32 out, 50.3MB) doubles as bf16 scratch:
  //   lo  [0, 25.2M):  q -> attn out (in-place) ; dead after Wo GEMM
  //   hi  [25.2M, 50.3M): h1 (ln1) -> h2 (ln2)
  //   MLP2 chunk c writes f32 rows [4096c,+4096) = bytes [12.58Mc, +12.58M);
  //   it only overlaps h2 chunks c' < 2c-2, all consumed by earlier MLP1.
  // ws (64,487,424 B):
  //   slot0 @0   : k -> res2      slot1 @SZ : v^T -> MLP hidden chunk
  //   weights @2*SZ: wqT,wkT,wvT,woT (1.18MB ea) + w1T,w2T (4.72MB ea)
  const size_t SZ = (size_t)M_ROWS * D_MODEL * 2;  // 25,165,824
  char* ws = (char*)d_ws;
  unsigned short* kbuf = (unsigned short*)(ws + 0);
  unsigned short* vtb  = (unsigned short*)(ws + 1 * SZ);
  unsigned short* res2 = kbuf;
  unsigned short* hid  = vtb;
  char* wp = ws + 2 * SZ;
  unsigned short* wqT = (unsigned short*)wp; wp += (size_t)768 * 768 * 2;
  unsigned short* wkT = (unsigned short*)wp; wp += (size_t)768 * 768 * 2;
  unsigned short* wvT = (unsigned short*)wp; wp += (size_t)768 * 768 * 2;
  unsigned short* woT = (unsigned short*)wp; wp += (size_t)768 * 768 * 2;
  unsigned short* w1T = (unsigned short*)wp; wp += (size_t)768 * 3072 * 2;
  unsigned short* w2T = (unsigned short*)wp; wp += (size_t)768 * 3072 * 2;

  unsigned short* qd = (unsigned short*)d_out;             // bf16 lo half
  unsigned short* h1 = qd + (size_t)M_ROWS * D_MODEL;      // bf16 hi half
  unsigned short* h2 = h1;

  const dim3 tb(32, 8, 1);
  wtr_k<<<dim3(24, 24), tb, 0, stream>>>(Wq, wqT, 768, 768);
  wtr_k<<<dim3(24, 24), tb, 0, stream>>>(Wk, wkT, 768, 768);
  wtr_k<<<dim3(24, 24), tb, 0, stream>>>(Wv, wvT, 768, 768);
  wtr_k<<<dim3(24, 24), tb, 0, stream>>>(Wo, woT, 768, 768);
  wtr_k<<<dim3(96, 24), tb, 0, stream>>>(W1, w1T, 768, 3072);
  wtr_k<<<dim3(24, 96), tb, 0, stream>>>(W2, w2T, 3072, 768);

  ln_k<1><<<M_ROWS, 256, 0, stream>>>(x, g1, bt1, h1);

  gemm_k<0><<<dim3(128, 6), 256, 0, stream>>>(h1, wqT, bq, qd,   nullptr, M_ROWS, 768, 768);
  gemm_k<0><<<dim3(128, 6), 256, 0, stream>>>(h1, wkT, bk, kbuf, nullptr, M_ROWS, 768, 768);
  gemm_k<4><<<dim3(128, 6), 256, 0, stream>>>(h1, wvT, bv, vtb,  nullptr, M_ROWS, 768, 768);

  attn_k<<<dim3(16, 12, 16), 256, 0, stream>>>(qd, kbuf, vtb, qd);

  gemm_k<2><<<dim3(128, 6), 256, 0, stream>>>(qd, woT, bo, res2, x, M_ROWS, 768, 768);

  ln_k<0><<<M_ROWS, 256, 0, stream>>>(res2, g2, bt2, h2);

  for (int c = 0; c < 4; ++c) {
    const size_t ro = (size_t)c * 4096;
    gemm_k<1><<<dim3(32, 24), 256, 0, stream>>>(h2 + ro * 768, w1T, bb1, hid,
        nullptr, 4096, 3072, 768);
    gemm_k<3><<<dim3(32, 6), 256, 0, stream>>>(hid, w2T, bb2,
        (float*)d_out + ro * 768, res2 + ro * 768, 4096, 768, 3072);
  }
}

// Round 7
// 770.045 us; speedup vs baseline: 3.1664x; 1.0237x over previous
//
#include <hip/hip_runtime.h>
#include <hip/hip_bf16.h>
#include <math.h>

#define D_MODEL 768
#define T_SEQ   1024
#define B_BATCH 16
#define MLP_DIM 3072
#define M_ROWS  (B_BATCH * T_SEQ)   // 16384

typedef __attribute__((ext_vector_type(8))) __bf16          bf16x8;
typedef __attribute__((ext_vector_type(4))) __bf16          bf16x4;
typedef __attribute__((ext_vector_type(4))) float           f32x4;

__device__ __forceinline__ float bf2f(unsigned short u) {
  union { unsigned int u; float f; } w; w.u = ((unsigned int)u) << 16; return w.f;
}
__device__ __forceinline__ unsigned short f2bf(float f) {
  union { float f; unsigned int u; } w; w.f = f;
  unsigned int r = (w.u + 0x7fffu + ((w.u >> 16) & 1u)) >> 16;
  return (unsigned short)r;
}
__device__ __forceinline__ float gelu_f(float x) {
  return 0.5f * x * (1.0f + erff(x * 0.70710678118654752f));
}
// async global->LDS, 16B per lane; LDS dest = base + lane*16 (linear)
__device__ __forceinline__ void gload16(const void* g, void* l) {
  __builtin_amdgcn_global_load_lds(
      (const __attribute__((address_space(1))) unsigned int*)g,
      (__attribute__((address_space(3))) unsigned int*)l, 16, 0, 0);
}

// ------- weight transpose+convert: dst[N=C][K=R] bf16 = src[R][C] f32 ------
__global__ void wtr_k(const float* __restrict__ src,
                      unsigned short* __restrict__ dst, int R, int C) {
  __shared__ float t[32][33];
  const int c0 = blockIdx.x * 32, r0 = blockIdx.y * 32;
  const int tx = threadIdx.x, ty = threadIdx.y;
  #pragma unroll
  for (int j = 0; j < 32; j += 8)
    t[ty + j][tx] = src[(size_t)(r0 + ty + j) * C + (c0 + tx)];
  __syncthreads();
  #pragma unroll
  for (int j = 0; j < 32; j += 8)
    dst[(size_t)(c0 + ty + j) * R + (r0 + tx)] = f2bf(t[tx][ty + j]);
}

// ---------- fused LayerNorm (stats + apply), one block per row -------------
template<int SRC_F32>
__global__ __launch_bounds__(256) void ln_k(const void* __restrict__ src,
    const float* __restrict__ g, const float* __restrict__ b,
    unsigned short* __restrict__ out) {
  const int row = blockIdx.x, tid = threadIdx.x;
  const size_t base = (size_t)row * D_MODEL;
  float v[3];
  #pragma unroll
  for (int i = 0; i < 3; ++i) {
    const int c = tid + (i << 8);
    v[i] = SRC_F32 ? ((const float*)src)[base + c]
                   : bf2f(((const unsigned short*)src)[base + c]);
  }
  float s  = v[0] + v[1] + v[2];
  float sq = v[0]*v[0] + v[1]*v[1] + v[2]*v[2];
  #pragma unroll
  for (int m = 32; m; m >>= 1) { s += __shfl_xor(s, m); sq += __shfl_xor(sq, m); }
  __shared__ float ps[4], pq[4];
  if ((tid & 63) == 0) { ps[tid >> 6] = s; pq[tid >> 6] = sq; }
  __syncthreads();
  s  = ps[0] + ps[1] + ps[2] + ps[3];
  sq = pq[0] + pq[1] + pq[2] + pq[3];
  const float mu  = s * (1.0f / 768.0f);
  const float var = sq * (1.0f / 768.0f) - mu * mu;
  const float inv = rsqrtf(var + 1e-5f);
  #pragma unroll
  for (int i = 0; i < 3; ++i) {
    const int c = tid + (i << 8);
    out[base + c] = f2bf((v[i] - mu) * inv * g[c] + b[c]);
  }
}

// ---- GEMM: C[M,N] = A[M,K](bf16) @ Bt[N,K]^T(bf16) + bias(f32) ------------
// m97 structure: linear LDS [128][32], global_load_lds width-16 staging.
// EP 0: bf16 store            | 1: gelu -> bf16
// EP 2: +resid(f32) -> bf16   | 3: gelu + resid(bf16) -> f32 (final output)
// EP 4: bf16 in V^T layout vt[(row>>10)*768 + col][row&1023]
template<int EP>
__global__ __launch_bounds__(256) void gemm_k(
    const unsigned short* __restrict__ Au, const unsigned short* __restrict__ Btu,
    const float* __restrict__ bias, void* __restrict__ outv,
    const void* __restrict__ residv, int M, int N, int K) {
  __shared__ __align__(16) __bf16 As[128][32];
  __shared__ __align__(16) __bf16 Bs[128][32];
  const __bf16* A  = (const __bf16*)Au;
  const __bf16* Bt = (const __bf16*)Btu;
  const int tid = threadIdx.x;
  const int lane = tid & 63, wid = tid >> 6;
  const int wr = wid >> 1, wc = wid & 1;
  const int brow = blockIdx.x * 128, bcol = blockIdx.y * 128;
  const int lr = lane & 15, lg = lane >> 4;
  f32x4 acc[4][4];
  #pragma unroll
  for (int m = 0; m < 4; ++m)
    #pragma unroll
    for (int n = 0; n < 4; ++n) acc[m][n] = (f32x4){0.f, 0.f, 0.f, 0.f};

  // per-wave staging source: 32 A-rows + 32 B-rows, 16B per lane
  const int srow = (wid << 5) + (lane >> 2);        // wave-local row 0..31
  const int scol = (lane & 3) << 3;                 // k-offset 0,8,16,24

  for (int k0 = 0; k0 < K; k0 += 32) {
    __syncthreads();
    const __bf16* ga = A  + (size_t)(brow + srow) * K + k0 + scol;
    const __bf16* gb = Bt + (size_t)(bcol + srow) * K + k0 + scol;
    gload16(ga,                 &As[(wid << 5)][0]);
    gload16(ga + (size_t)16 * K, &As[(wid << 5) + 16][0]);
    gload16(gb,                 &Bs[(wid << 5)][0]);
    gload16(gb + (size_t)16 * K, &Bs[(wid << 5) + 16][0]);
    __syncthreads();
    bf16x8 af[4], bfr[4];
    #pragma unroll
    for (int m = 0; m < 4; ++m) af[m]  = *(const bf16x8*)(&As[wr*64 + m*16 + lr][lg*8]);
    #pragma unroll
    for (int n = 0; n < 4; ++n) bfr[n] = *(const bf16x8*)(&Bs[wc*64 + n*16 + lr][lg*8]);
    #pragma unroll
    for (int m = 0; m < 4; ++m)
      #pragma unroll
      for (int n = 0; n < 4; ++n)
        acc[m][n] = __builtin_amdgcn_mfma_f32_16x16x32_bf16(af[m], bfr[n], acc[m][n], 0, 0, 0);
  }

  #pragma unroll
  for (int n = 0; n < 4; ++n) {
    const int col = bcol + wc*64 + n*16 + lr;
    const float bv = bias[col];
    #pragma unroll
    for (int m = 0; m < 4; ++m) {
      const int row0 = brow + wr*64 + m*16 + lg*4;
      #pragma unroll
      for (int r = 0; r < 4; ++r) {
        const int gr = row0 + r;
        const size_t o = (size_t)gr * N + col;
        float v = acc[m][n][r] + bv;
        if (EP == 0)      ((unsigned short*)outv)[o] = f2bf(v);
        else if (EP == 1) ((unsigned short*)outv)[o] = f2bf(gelu_f(v));
        else if (EP == 2) ((unsigned short*)outv)[o] = f2bf(v + ((const float*)residv)[o]);
        else if (EP == 3) ((float*)outv)[o] = gelu_f(v) + bf2f(((const unsigned short*)residv)[o]);
        else ((unsigned short*)outv)[(((size_t)(gr >> 10) * D_MODEL + col) << 10) + (gr & 1023)] = f2bf(v);
      }
    }
  }
}

// ---------------- flash attention: block = (b, h, 128 q-rows), 8 waves -----
// Swapped QK^T (S^T = K·Q^T) -> per-lane row-local softmax; online m/l;
// PV as O^T = V^T·P^T. In-place on q (block reads exactly the region it
// writes; regions disjoint across blocks).
__global__ __launch_bounds__(512) void attn_k(
    const unsigned short* qu, const unsigned short* __restrict__ ku,
    const unsigned short* __restrict__ vtu, unsigned short* attn) {
  __shared__ __align__(16) __bf16 Kl[64][72];
  __shared__ __align__(16) __bf16 Vl[64][72];
  __shared__ __align__(16) __bf16 Pl[8][16][72];
  const __bf16* qg  = (const __bf16*)qu;
  const __bf16* kg  = (const __bf16*)ku;
  const __bf16* vtg = (const __bf16*)vtu;
  const int b = blockIdx.z, h = blockIdx.y, q0 = blockIdx.x * 128;
  const int tid = threadIdx.x, lane = tid & 63, w = tid >> 6;
  const int lr = lane & 15, lg = lane >> 4;
  const float scale = 0.03608439182435161f; // 1/sqrt(768)

  const int qrow = b * T_SEQ + q0 + w * 16 + lr;
  const __bf16* qp = qg + (size_t)qrow * D_MODEL + h * 64 + lg * 8;
  const bf16x8 qa0 = *(const bf16x8*)(qp);
  const bf16x8 qa1 = *(const bf16x8*)(qp + 32);

  const __bf16* kb = kg  + (size_t)b * T_SEQ * D_MODEL + h * 64;
  const __bf16* vb = vtg + ((size_t)b * D_MODEL + h * 64) * T_SEQ;

  f32x4 o[4];
  #pragma unroll
  for (int m = 0; m < 4; ++m) o[m] = (f32x4){0.f, 0.f, 0.f, 0.f};
  float m_run = -1e30f, l_run = 0.f;

  for (int kv0 = 0; kv0 < T_SEQ; kv0 += 64) {
    __syncthreads();
    // stage 64x64 K-tile (row-major) and V^T-tile: 512 slots of 8 bf16
    {
      const int r = tid >> 3, c = (tid & 7) << 3;
      *(bf16x8*)(&Kl[r][c]) = *(const bf16x8*)(kb + (size_t)(kv0 + r) * D_MODEL + c);
      *(bf16x8*)(&Vl[r][c]) = *(const bf16x8*)(vb + (size_t)r * T_SEQ + kv0 + c);
    }
    __syncthreads();

    // QK^T (swapped): s[m] holds S^T[kv = 16m+4lg+r][q = lr]
    f32x4 s[4];
    __builtin_amdgcn_s_setprio(1);
    #pragma unroll
    for (int m = 0; m < 4; ++m) {
      s[m] = (f32x4){0.f, 0.f, 0.f, 0.f};
      const bf16x8 kf0 = *(const bf16x8*)(&Kl[m*16 + lr][lg*8]);
      const bf16x8 kf1 = *(const bf16x8*)(&Kl[m*16 + lr][32 + lg*8]);
      s[m] = __builtin_amdgcn_mfma_f32_16x16x32_bf16(kf0, qa0, s[m], 0, 0, 0);
      s[m] = __builtin_amdgcn_mfma_f32_16x16x32_bf16(kf1, qa1, s[m], 0, 0, 0);
    }
    __builtin_amdgcn_s_setprio(0);
    // online softmax for q = lr (16 values in-lane, reduce across lg)
    float sv[4][4];
    float tm = -1e30f;
    #pragma unroll
    for (int m = 0; m < 4; ++m)
      #pragma unroll
      for (int r = 0; r < 4; ++r) {
        sv[m][r] = s[m][r] * scale;
        tm = fmaxf(tm, sv[m][r]);
      }
    tm = fmaxf(tm, __shfl_xor(tm, 16));
    tm = fmaxf(tm, __shfl_xor(tm, 32));
    const float mn = fmaxf(m_run, tm);
    const float sc = __expf(m_run - mn);
    float ts = 0.f;
    bf16x4 pk[4];
    #pragma unroll
    for (int m = 0; m < 4; ++m)
      #pragma unroll
      for (int r = 0; r < 4; ++r) {
        const float pp = __expf(sv[m][r] - mn);
        ts += pp;
        pk[m][r] = (__bf16)pp;
      }
    ts += __shfl_xor(ts, 16);
    ts += __shfl_xor(ts, 32);
    l_run = l_run * sc + ts;
    m_run = mn;
    #pragma unroll
    for (int m = 0; m < 4; ++m)
      #pragma unroll
      for (int r = 0; r < 4; ++r) o[m][r] *= sc;
    // P bounce through per-wave LDS into B-fragment layout
    #pragma unroll
    for (int m = 0; m < 4; ++m)
      *(bf16x4*)(&Pl[w][lr][16*m + 4*lg]) = pk[m];
    const bf16x8 pf0 = *(const bf16x8*)(&Pl[w][lr][lg*8]);
    const bf16x8 pf1 = *(const bf16x8*)(&Pl[w][lr][32 + lg*8]);
    // PV: O^T[d = 16m+4lg+r][q = lr]
    __builtin_amdgcn_s_setprio(1);
    #pragma unroll
    for (int m = 0; m < 4; ++m) {
      const bf16x8 vf0 = *(const bf16x8*)(&Vl[m*16 + lr][lg*8]);
      const bf16x8 vf1 = *(const bf16x8*)(&Vl[m*16 + lr][32 + lg*8]);
      o[m] = __builtin_amdgcn_mfma_f32_16x16x32_bf16(vf0, pf0, o[m], 0, 0, 0);
      o[m] = __builtin_amdgcn_mfma_f32_16x16x32_bf16(vf1, pf1, o[m], 0, 0, 0);
    }
    __builtin_amdgcn_s_setprio(0);
  }

  const float inv = 1.0f / l_run;
  unsigned short* op = attn + (size_t)qrow * D_MODEL + h * 64;
  #pragma unroll
  for (int m = 0; m < 4; ++m) {
    bf16x4 ov;
    #pragma unroll
    for (int r = 0; r < 4; ++r) ov[r] = (__bf16)(o[m][r] * inv);
    *(bf16x4*)(op + 16*m + 4*lg) = ov;
  }
}

// ---------------------------------------------------------------------------
extern "C" void kernel_launch(void* const* d_in, const int* in_sizes, int n_in,
                              void* d_out, int out_size, void* d_ws, size_t ws_size,
                              hipStream_t stream) {
  const float* x   = (const float*)d_in[0];
  const float* Wq  = (const float*)d_in[1];
  const float* bq  = (const float*)d_in[2];
  const float* Wk  = (const float*)d_in[3];
  const float* bk  = (const float*)d_in[4];
  const float* Wv  = (const float*)d_in[5];
  const float* bv  = (const float*)d_in[6];
  const float* Wo  = (const float*)d_in[7];
  const float* bo  = (const float*)d_in[8];
  const float* g1  = (const float*)d_in[9];
  const float* bt1 = (const float*)d_in[10];
  const float* g2  = (const float*)d_in[11];
  const float* bt2 = (const float*)d_in[12];
  const float* W1  = (const float*)d_in[13];
  const float* bb1 = (const float*)d_in[14];
  const float* W2  = (const float*)d_in[15];
  const float* bb2 = (const float*)d_in[16];

  // d_out (f32 out, 50.3MB) doubles as bf16 scratch:
  //   lo  [0, 25.2M):  q -> attn out (in-place) ; dead after Wo GEMM
  //   hi  [25.2M, 50.3M): h1 (ln1) -> h2 (ln2)
  //   MLP2 chunk c writes f32 rows [4096c,+4096); only overlaps h2 chunks
  //   c' < 2c-2, all consumed by earlier MLP1 launches.
  // ws (64,487,424 B):
  //   slot0 @0   : k -> res2      slot1 @SZ : v^T -> MLP hidden chunk
  //   weights @2*SZ: wqT,wkT,wvT,woT + w1T,w2T
  const size_t SZ = (size_t)M_ROWS * D_MODEL * 2;  // 25,165,824
  char* ws = (char*)d_ws;
  unsigned short* kbuf = (unsigned short*)(ws + 0);
  unsigned short* vtb  = (unsigned short*)(ws + 1 * SZ);
  unsigned short* res2 = kbuf;
  unsigned short* hid  = vtb;
  char* wp = ws + 2 * SZ;
  unsigned short* wqT = (unsigned short*)wp; wp += (size_t)768 * 768 * 2;
  unsigned short* wkT = (unsigned short*)wp; wp += (size_t)768 * 768 * 2;
  unsigned short* wvT = (unsigned short*)wp; wp += (size_t)768 * 768 * 2;
  unsigned short* woT = (unsigned short*)wp; wp += (size_t)768 * 768 * 2;
  unsigned short* w1T = (unsigned short*)wp; wp += (size_t)768 * 3072 * 2;
  unsigned short* w2T = (unsigned short*)wp; wp += (size_t)768 * 3072 * 2;

  unsigned short* qd = (unsigned short*)d_out;             // bf16 lo half
  unsigned short* h1 = qd + (size_t)M_ROWS * D_MODEL;      // bf16 hi half
  unsigned short* h2 = h1;

  const dim3 tb(32, 8, 1);
  wtr_k<<<dim3(24, 24), tb, 0, stream>>>(Wq, wqT, 768, 768);
  wtr_k<<<dim3(24, 24), tb, 0, stream>>>(Wk, wkT, 768, 768);
  wtr_k<<<dim3(24, 24), tb, 0, stream>>>(Wv, wvT, 768, 768);
  wtr_k<<<dim3(24, 24), tb, 0, stream>>>(Wo, woT, 768, 768);
  wtr_k<<<dim3(96, 24), tb, 0, stream>>>(W1, w1T, 768, 3072);
  wtr_k<<<dim3(24, 96), tb, 0, stream>>>(W2, w2T, 3072, 768);

  ln_k<1><<<M_ROWS, 256, 0, stream>>>(x, g1, bt1, h1);

  gemm_k<0><<<dim3(128, 6), 256, 0, stream>>>(h1, wqT, bq, qd,   nullptr, M_ROWS, 768, 768);
  gemm_k<0><<<dim3(128, 6), 256, 0, stream>>>(h1, wkT, bk, kbuf, nullptr, M_ROWS, 768, 768);
  gemm_k<4><<<dim3(128, 6), 256, 0, stream>>>(h1, wvT, bv, vtb,  nullptr, M_ROWS, 768, 768);

  attn_k<<<dim3(8, 12, 16), 512, 0, stream>>>(qd, kbuf, vtb, qd);

  gemm_k<2><<<dim3(128, 6), 256, 0, stream>>>(qd, woT, bo, res2, x, M_ROWS, 768, 768);

  ln_k<0><<<M_ROWS, 256, 0, stream>>>(res2, g2, bt2, h2);

  for (int c = 0; c < 4; ++c) {
    const size_t ro = (size_t)c * 4096;
    gemm_k<1><<<dim3(32, 24), 256, 0, stream>>>(h2 + ro * 768, w1T, bb1, hid,
        nullptr, 4096, 3072, 768);
    gemm_k<3><<<dim3(32, 6), 256, 0, stream>>>(hid, w2T, bb2,
        (float*)d_out + ro * 768, res2 + ro * 768, 4096, 768, 3072);
  }
}

// Round 8
// 732.278 us; speedup vs baseline: 3.3297x; 1.0516x over previous
//
#include <hip/hip_runtime.h>
#include <hip/hip_bf16.h>
#include <math.h>

#define D_MODEL 768
#define T_SEQ   1024
#define B_BATCH 16
#define MLP_DIM 3072
#define M_ROWS  (B_BATCH * T_SEQ)   // 16384

typedef __attribute__((ext_vector_type(8))) __bf16          bf16x8;
typedef __attribute__((ext_vector_type(4))) __bf16          bf16x4;
typedef __attribute__((ext_vector_type(4))) float           f32x4;

__device__ __forceinline__ float bf2f(unsigned short u) {
  union { unsigned int u; float f; } w; w.u = ((unsigned int)u) << 16; return w.f;
}
__device__ __forceinline__ unsigned short f2bf(float f) {
  union { float f; unsigned int u; } w; w.f = f;
  unsigned int r = (w.u + 0x7fffu + ((w.u >> 16) & 1u)) >> 16;
  return (unsigned short)r;
}
__device__ __forceinline__ float gelu_f(float x) {
  return 0.5f * x * (1.0f + erff(x * 0.70710678118654752f));
}
// async global->LDS, 16B per lane; LDS dest = wave-uniform base + lane*16
__device__ __forceinline__ void gload16(const void* g, void* l) {
  __builtin_amdgcn_global_load_lds(
      (const __attribute__((address_space(1))) unsigned int*)g,
      (__attribute__((address_space(3))) unsigned int*)l, 16, 0, 0);
}

// ------- weight transpose+convert: dst[N=C][K=R] bf16 = src[R][C] f32 ------
__global__ void wtr_k(const float* __restrict__ src,
                      unsigned short* __restrict__ dst, int R, int C) {
  __shared__ float t[32][33];
  const int c0 = blockIdx.x * 32, r0 = blockIdx.y * 32;
  const int tx = threadIdx.x, ty = threadIdx.y;
  #pragma unroll
  for (int j = 0; j < 32; j += 8)
    t[ty + j][tx] = src[(size_t)(r0 + ty + j) * C + (c0 + tx)];
  __syncthreads();
  #pragma unroll
  for (int j = 0; j < 32; j += 8)
    dst[(size_t)(c0 + ty + j) * R + (r0 + tx)] = f2bf(t[tx][ty + j]);
}

// ------- concat 3 bias vectors of 768 f32 --------------------------------
__global__ void bcat_k(const float* __restrict__ a, const float* __restrict__ b,
                       const float* __restrict__ c, float* __restrict__ o) {
  const int i = blockIdx.x * 256 + threadIdx.x;
  if (i < 768) { o[i] = a[i]; o[i + 768] = b[i]; o[i + 1536] = c[i]; }
}

// ---------- fused LayerNorm (stats + apply), one block per row -------------
template<int SRC_F32>
__global__ __launch_bounds__(256) void ln_k(const void* __restrict__ src,
    const float* __restrict__ g, const float* __restrict__ b,
    unsigned short* __restrict__ out) {
  const int row = blockIdx.x, tid = threadIdx.x;
  const size_t base = (size_t)row * D_MODEL;
  float v[3];
  #pragma unroll
  for (int i = 0; i < 3; ++i) {
    const int c = tid + (i << 8);
    v[i] = SRC_F32 ? ((const float*)src)[base + c]
                   : bf2f(((const unsigned short*)src)[base + c]);
  }
  float s  = v[0] + v[1] + v[2];
  float sq = v[0]*v[0] + v[1]*v[1] + v[2]*v[2];
  #pragma unroll
  for (int m = 32; m; m >>= 1) { s += __shfl_xor(s, m); sq += __shfl_xor(sq, m); }
  __shared__ float ps[4], pq[4];
  if ((tid & 63) == 0) { ps[tid >> 6] = s; pq[tid >> 6] = sq; }
  __syncthreads();
  s  = ps[0] + ps[1] + ps[2] + ps[3];
  sq = pq[0] + pq[1] + pq[2] + pq[3];
  const float mu  = s * (1.0f / 768.0f);
  const float var = sq * (1.0f / 768.0f) - mu * mu;
  const float inv = rsqrtf(var + 1e-5f);
  #pragma unroll
  for (int i = 0; i < 3; ++i) {
    const int c = tid + (i << 8);
    out[base + c] = f2bf((v[i] - mu) * inv * g[c] + b[c]);
  }
}

// ---- GEMM: C[M,N] = A[M,K](bf16) @ Bt[N,K]^T(bf16) + bias(f32) ------------
// 2-phase pipeline: double-buffered LDS, counted vmcnt, raw barriers.
// EP 0: bf16 store            | 1: gelu -> bf16
// EP 2: +resid(f32) -> bf16   | 3: gelu + resid(bf16) -> f32 (final output)
// EP 5: fused QKV split store (outv=q, residv=k, aux=v^T layout)
template<int EP>
__global__ __launch_bounds__(256) void gemm_k(
    const unsigned short* __restrict__ Au, const unsigned short* __restrict__ Btu,
    const float* __restrict__ bias, void* __restrict__ outv,
    const void* __restrict__ residv, void* __restrict__ aux,
    int M, int N, int K) {
  __shared__ __align__(16) __bf16 As[2][128][32];
  __shared__ __align__(16) __bf16 Bs[2][128][32];
  const __bf16* A  = (const __bf16*)Au;
  const __bf16* Bt = (const __bf16*)Btu;
  const int tid = threadIdx.x;
  const int lane = tid & 63, wid = tid >> 6;
  const int wr = wid >> 1, wc = wid & 1;
  const int brow = blockIdx.x * 128, bcol = blockIdx.y * 128;
  const int lr = lane & 15, lg = lane >> 4;
  f32x4 acc[4][4];
  #pragma unroll
  for (int m = 0; m < 4; ++m)
    #pragma unroll
    for (int n = 0; n < 4; ++n) acc[m][n] = (f32x4){0.f, 0.f, 0.f, 0.f};

  // per-wave staging: 32 A-rows + 32 B-rows, 16B per lane, linear LDS dest
  const int srow = (wid << 5) + (lane >> 2);
  const int scol = (lane & 3) << 3;
  const __bf16* gA = A  + (size_t)(brow + srow) * K + scol;
  const __bf16* gB = Bt + (size_t)(bcol + srow) * K + scol;

#define STAGE_(buf_, k0_) do {                                        \
    gload16(gA + (k0_),                   &As[buf_][(wid << 5)][0]);  \
    gload16(gA + (k0_) + 16 * (size_t)K,  &As[buf_][(wid << 5) + 16][0]); \
    gload16(gB + (k0_),                   &Bs[buf_][(wid << 5)][0]);  \
    gload16(gB + (k0_) + 16 * (size_t)K,  &Bs[buf_][(wid << 5) + 16][0]); \
  } while (0)

  STAGE_(0, 0);
  int cur = 0;
  for (int k0 = 0; k0 < K; k0 += 32, cur ^= 1) {
    if (k0 + 32 < K) {
      STAGE_(cur ^ 1, k0 + 32);
      asm volatile("s_waitcnt vmcnt(4)" ::: "memory");   // current tile landed; 4 prefetch in flight
    } else {
      asm volatile("s_waitcnt vmcnt(0)" ::: "memory");
    }
    __builtin_amdgcn_s_barrier();
    __builtin_amdgcn_sched_barrier(0);
    bf16x8 af[4], bfr[4];
    #pragma unroll
    for (int m = 0; m < 4; ++m) af[m]  = *(const bf16x8*)(&As[cur][wr*64 + m*16 + lr][lg*8]);
    #pragma unroll
    for (int n = 0; n < 4; ++n) bfr[n] = *(const bf16x8*)(&Bs[cur][wc*64 + n*16 + lr][lg*8]);
    #pragma unroll
    for (int m = 0; m < 4; ++m)
      #pragma unroll
      for (int n = 0; n < 4; ++n)
        acc[m][n] = __builtin_amdgcn_mfma_f32_16x16x32_bf16(af[m], bfr[n], acc[m][n], 0, 0, 0);
    asm volatile("s_waitcnt lgkmcnt(0)" ::: "memory");   // LDS reads done before next STAGE overwrites
    __builtin_amdgcn_sched_barrier(0);
    __builtin_amdgcn_s_barrier();
    __builtin_amdgcn_sched_barrier(0);
  }
#undef STAGE_

  const int seg  = (EP == 5) ? (bcol / 768) : 0;     // block-uniform
  unsigned short* qkvp = nullptr;
  if (EP == 5)
    qkvp = (seg == 0) ? (unsigned short*)outv
         : (seg == 1) ? (unsigned short*)residv : (unsigned short*)aux;

  #pragma unroll
  for (int n = 0; n < 4; ++n) {
    const int col = bcol + wc*64 + n*16 + lr;
    const float bv = bias[col];
    #pragma unroll
    for (int m = 0; m < 4; ++m) {
      const int row0 = brow + wr*64 + m*16 + lg*4;
      #pragma unroll
      for (int r = 0; r < 4; ++r) {
        const int gr = row0 + r;
        const size_t o = (size_t)gr * N + col;
        float v = acc[m][n][r] + bv;
        if (EP == 0)      ((unsigned short*)outv)[o] = f2bf(v);
        else if (EP == 1) ((unsigned short*)outv)[o] = f2bf(gelu_f(v));
        else if (EP == 2) ((unsigned short*)outv)[o] = f2bf(v + ((const float*)residv)[o]);
        else if (EP == 3) ((float*)outv)[o] = gelu_f(v) + bf2f(((const unsigned short*)residv)[o]);
        else { // EP 5
          const int colL = col - seg * 768;
          if (seg < 2) qkvp[(size_t)gr * 768 + colL] = f2bf(v);
          else qkvp[(((size_t)(gr >> 10) * D_MODEL + colL) << 10) + (gr & 1023)] = f2bf(v);
        }
      }
    }
  }
}

// ---------------- flash attention: block = (b, h, 256 q-rows), 8 waves -----
// Swapped QK^T -> per-lane row-local softmax; online m/l; PV as O^T = V^T P^T.
// Wave w owns 32 rows (two 16-row groups g=0,1 processed sequentially).
// grid.x = b*12+h so all q-blocks of one (b,h) share id%8 -> same XCD (L2).
// In-place on q: all Q reads precede the first loop barrier; writes after.
__global__ __launch_bounds__(512) void attn_k(
    const unsigned short* qu, const unsigned short* __restrict__ ku,
    const unsigned short* __restrict__ vtu, unsigned short* attn) {
  __shared__ __align__(16) __bf16 Kl[64][72];
  __shared__ __align__(16) __bf16 Vl[64][72];
  __shared__ __align__(16) __bf16 Pl[8][16][72];
  const __bf16* qg  = (const __bf16*)qu;
  const __bf16* kg  = (const __bf16*)ku;
  const __bf16* vtg = (const __bf16*)vtu;
  const int bh = blockIdx.x, b = bh / 12, h = bh % 12;
  const int q0 = blockIdx.y * 256;
  const int tid = threadIdx.x, lane = tid & 63, w = tid >> 6;
  const int lr = lane & 15, lg = lane >> 4;
  const float scale = 0.03608439182435161f; // 1/sqrt(768)

  bf16x8 qa[2][2];
  #pragma unroll
  for (int g = 0; g < 2; ++g) {
    const int qrow = b * T_SEQ + q0 + w * 32 + g * 16 + lr;
    const __bf16* qp = qg + (size_t)qrow * D_MODEL + h * 64 + lg * 8;
    qa[g][0] = *(const bf16x8*)(qp);
    qa[g][1] = *(const bf16x8*)(qp + 32);
  }

  const __bf16* kb = kg  + (size_t)b * T_SEQ * D_MODEL + h * 64;
  const __bf16* vb = vtg + ((size_t)b * D_MODEL + h * 64) * T_SEQ;

  f32x4 o[2][4];
  float m_run[2] = {-1e30f, -1e30f}, l_run[2] = {0.f, 0.f};
  #pragma unroll
  for (int g = 0; g < 2; ++g)
    #pragma unroll
    for (int m = 0; m < 4; ++m) o[g][m] = (f32x4){0.f, 0.f, 0.f, 0.f};

  for (int kv0 = 0; kv0 < T_SEQ; kv0 += 64) {
    __syncthreads();
    { // stage 64x64 K-tile and V^T-tile: 512 threads x 8 bf16
      const int r = tid >> 3, c = (tid & 7) << 3;
      *(bf16x8*)(&Kl[r][c]) = *(const bf16x8*)(kb + (size_t)(kv0 + r) * D_MODEL + c);
      *(bf16x8*)(&Vl[r][c]) = *(const bf16x8*)(vb + (size_t)r * T_SEQ + kv0 + c);
    }
    __syncthreads();

    #pragma unroll
    for (int g = 0; g < 2; ++g) {
      // QK^T (swapped): s[m] holds S^T[kv = 16m+4lg+r][q-row lr of group g]
      f32x4 s[4];
      __builtin_amdgcn_s_setprio(1);
      #pragma unroll
      for (int m = 0; m < 4; ++m) {
        s[m] = (f32x4){0.f, 0.f, 0.f, 0.f};
        const bf16x8 kf0 = *(const bf16x8*)(&Kl[m*16 + lr][lg*8]);
        const bf16x8 kf1 = *(const bf16x8*)(&Kl[m*16 + lr][32 + lg*8]);
        s[m] = __builtin_amdgcn_mfma_f32_16x16x32_bf16(kf0, qa[g][0], s[m], 0, 0, 0);
        s[m] = __builtin_amdgcn_mfma_f32_16x16x32_bf16(kf1, qa[g][1], s[m], 0, 0, 0);
      }
      __builtin_amdgcn_s_setprio(0);
      float sv[4][4], tm = -1e30f;
      #pragma unroll
      for (int m = 0; m < 4; ++m)
        #pragma unroll
        for (int r = 0; r < 4; ++r) {
          sv[m][r] = s[m][r] * scale;
          tm = fmaxf(tm, sv[m][r]);
        }
      tm = fmaxf(tm, __shfl_xor(tm, 16));
      tm = fmaxf(tm, __shfl_xor(tm, 32));
      const float mn = fmaxf(m_run[g], tm);
      const float sc = __expf(m_run[g] - mn);
      float ts = 0.f;
      bf16x4 pk[4];
      #pragma unroll
      for (int m = 0; m < 4; ++m)
        #pragma unroll
        for (int r = 0; r < 4; ++r) {
          const float pp = __expf(sv[m][r] - mn);
          ts += pp;
          pk[m][r] = (__bf16)pp;
        }
      ts += __shfl_xor(ts, 16);
      ts += __shfl_xor(ts, 32);
      l_run[g] = l_run[g] * sc + ts;
      m_run[g] = mn;
      #pragma unroll
      for (int m = 0; m < 4; ++m)
        #pragma unroll
        for (int r = 0; r < 4; ++r) o[g][m][r] *= sc;
      // P bounce through per-wave LDS into B-fragment layout (wave-local,
      // per-wave DS ops are in-order so g=1 overwrite is safe)
      #pragma unroll
      for (int m = 0; m < 4; ++m)
        *(bf16x4*)(&Pl[w][lr][16*m + 4*lg]) = pk[m];
      const bf16x8 pf0 = *(const bf16x8*)(&Pl[w][lr][lg*8]);
      const bf16x8 pf1 = *(const bf16x8*)(&Pl[w][lr][32 + lg*8]);
      __builtin_amdgcn_s_setprio(1);
      #pragma unroll
      for (int m = 0; m < 4; ++m) {
        const bf16x8 vf0 = *(const bf16x8*)(&Vl[m*16 + lr][lg*8]);
        const bf16x8 vf1 = *(const bf16x8*)(&Vl[m*16 + lr][32 + lg*8]);
        o[g][m] = __builtin_amdgcn_mfma_f32_16x16x32_bf16(vf0, pf0, o[g][m], 0, 0, 0);
        o[g][m] = __builtin_amdgcn_mfma_f32_16x16x32_bf16(vf1, pf1, o[g][m], 0, 0, 0);
      }
      __builtin_amdgcn_s_setprio(0);
    }
  }

  #pragma unroll
  for (int g = 0; g < 2; ++g) {
    const float inv = 1.0f / l_run[g];
    const int qrow = b * T_SEQ + q0 + w * 32 + g * 16 + lr;
    unsigned short* op = attn + (size_t)qrow * D_MODEL + h * 64;
    #pragma unroll
    for (int m = 0; m < 4; ++m) {
      bf16x4 ov;
      #pragma unroll
      for (int r = 0; r < 4; ++r) ov[r] = (__bf16)(o[g][m][r] * inv);
      *(bf16x4*)(op + 16*m + 4*lg) = ov;
    }
  }
}

// ---------------------------------------------------------------------------
extern "C" void kernel_launch(void* const* d_in, const int* in_sizes, int n_in,
                              void* d_out, int out_size, void* d_ws, size_t ws_size,
                              hipStream_t stream) {
  const float* x   = (const float*)d_in[0];
  const float* Wq  = (const float*)d_in[1];
  const float* bq  = (const float*)d_in[2];
  const float* Wk  = (const float*)d_in[3];
  const float* bk  = (const float*)d_in[4];
  const float* Wv  = (const float*)d_in[5];
  const float* bv  = (const float*)d_in[6];
  const float* Wo  = (const float*)d_in[7];
  const float* bo  = (const float*)d_in[8];
  const float* g1  = (const float*)d_in[9];
  const float* bt1 = (const float*)d_in[10];
  const float* g2  = (const float*)d_in[11];
  const float* bt2 = (const float*)d_in[12];
  const float* W1  = (const float*)d_in[13];
  const float* bb1 = (const float*)d_in[14];
  const float* W2  = (const float*)d_in[15];
  const float* bb2 = (const float*)d_in[16];

  // d_out (f32 out, 50.3MB) doubles as bf16 scratch:
  //   lo: q -> attn out (in-place), dead after Wo GEMM
  //   hi: h1 (ln1) -> h2 (ln2); MLP2 chunk c's f32 writes only overlap
  //       h2 chunks already consumed by earlier MLP1 launches.
  // ws (~64.6 MB): slot0 k->res2, slot1 v^T->hid, wqkvT, woT, w1T, w2T, bqkv
  const size_t SZ = (size_t)M_ROWS * D_MODEL * 2;  // 25,165,824
  char* ws = (char*)d_ws;
  unsigned short* kbuf = (unsigned short*)(ws + 0);
  unsigned short* vtb  = (unsigned short*)(ws + 1 * SZ);
  unsigned short* res2 = kbuf;
  unsigned short* hid  = vtb;
  char* wp = ws + 2 * SZ;
  unsigned short* wqkvT = (unsigned short*)wp; wp += (size_t)2304 * 768 * 2;
  unsigned short* woT   = (unsigned short*)wp; wp += (size_t)768 * 768 * 2;
  unsigned short* w1T   = (unsigned short*)wp; wp += (size_t)768 * 3072 * 2;
  unsigned short* w2T   = (unsigned short*)wp; wp += (size_t)768 * 3072 * 2;
  float*          bqkv  = (float*)wp;          wp += 2304 * 4;

  unsigned short* qd = (unsigned short*)d_out;             // bf16 lo half
  unsigned short* h1 = qd + (size_t)M_ROWS * D_MODEL;      // bf16 hi half
  unsigned short* h2 = h1;

  const dim3 tb(32, 8, 1);
  wtr_k<<<dim3(24, 24), tb, 0, stream>>>(Wq, wqkvT, 768, 768);
  wtr_k<<<dim3(24, 24), tb, 0, stream>>>(Wk, wqkvT + (size_t)768 * 768, 768, 768);
  wtr_k<<<dim3(24, 24), tb, 0, stream>>>(Wv, wqkvT + (size_t)1536 * 768, 768, 768);
  wtr_k<<<dim3(24, 24), tb, 0, stream>>>(Wo, woT, 768, 768);
  wtr_k<<<dim3(96, 24), tb, 0, stream>>>(W1, w1T, 768, 3072);
  wtr_k<<<dim3(24, 96), tb, 0, stream>>>(W2, w2T, 3072, 768);
  bcat_k<<<3, 256, 0, stream>>>(bq, bk, bv, bqkv);

  ln_k<1><<<M_ROWS, 256, 0, stream>>>(x, g1, bt1, h1);

  gemm_k<5><<<dim3(128, 18), 256, 0, stream>>>(h1, wqkvT, bqkv, qd, kbuf, vtb,
                                               M_ROWS, 2304, 768);

  attn_k<<<dim3(192, 4), 512, 0, stream>>>(qd, kbuf, vtb, qd);

  gemm_k<2><<<dim3(128, 6), 256, 0, stream>>>(qd, woT, bo, res2, x, nullptr,
                                              M_ROWS, 768, 768);

  ln_k<0><<<M_ROWS, 256, 0, stream>>>(res2, g2, bt2, h2);

  for (int c = 0; c < 4; ++c) {
    const size_t ro = (size_t)c * 4096;
    gemm_k<1><<<dim3(32, 24), 256, 0, stream>>>(h2 + ro * 768, w1T, bb1, hid,
        nullptr, nullptr, 4096, 3072, 768);
    gemm_k<3><<<dim3(32, 6), 256, 0, stream>>>(hid, w2T, bb2,
        (float*)d_out + ro * 768, res2 + ro * 768, nullptr, 4096, 768, 3072);
  }
}

// Round 9
// 538.100 us; speedup vs baseline: 4.5312x; 1.3609x over previous
//
#include <hip/hip_runtime.h>
#include <hip/hip_bf16.h>
#include <math.h>

#define D_MODEL 768
#define T_SEQ   1024
#define B_BATCH 16
#define MLP_DIM 3072
#define M_ROWS  (B_BATCH * T_SEQ)   // 16384

typedef __attribute__((ext_vector_type(8))) __bf16          bf16x8;
typedef __attribute__((ext_vector_type(4))) __bf16          bf16x4;
typedef __attribute__((ext_vector_type(4))) float           f32x4;

__device__ __forceinline__ float bf2f(unsigned short u) {
  union { unsigned int u; float f; } w; w.u = ((unsigned int)u) << 16; return w.f;
}
__device__ __forceinline__ unsigned short f2bf(float f) {
  union { float f; unsigned int u; } w; w.f = f;
  unsigned int r = (w.u + 0x7fffu + ((w.u >> 16) & 1u)) >> 16;
  return (unsigned short)r;
}
__device__ __forceinline__ float gelu_f(float x) {
  return 0.5f * x * (1.0f + erff(x * 0.70710678118654752f));
}
// async global->LDS, 16B per lane; LDS dest = wave-uniform base + lane*16
__device__ __forceinline__ void gload16(const void* g, void* l) {
  __builtin_amdgcn_global_load_lds(
      (const __attribute__((address_space(1))) unsigned int*)g,
      (__attribute__((address_space(3))) unsigned int*)l, 16, 0, 0);
}

// ------- weight transpose+convert: dst[N=C][K=R] bf16 = src[R][C] f32 ------
__global__ void wtr_k(const float* __restrict__ src,
                      unsigned short* __restrict__ dst, int R, int C) {
  __shared__ float t[32][33];
  const int c0 = blockIdx.x * 32, r0 = blockIdx.y * 32;
  const int tx = threadIdx.x, ty = threadIdx.y;
  #pragma unroll
  for (int j = 0; j < 32; j += 8)
    t[ty + j][tx] = src[(size_t)(r0 + ty + j) * C + (c0 + tx)];
  __syncthreads();
  #pragma unroll
  for (int j = 0; j < 32; j += 8)
    dst[(size_t)(c0 + ty + j) * R + (r0 + tx)] = f2bf(t[tx][ty + j]);
}

// ------- concat 3 bias vectors of 768 f32 --------------------------------
__global__ void bcat_k(const float* __restrict__ a, const float* __restrict__ b,
                       const float* __restrict__ c, float* __restrict__ o) {
  const int i = blockIdx.x * 256 + threadIdx.x;
  if (i < 768) { o[i] = a[i]; o[i + 768] = b[i]; o[i + 1536] = c[i]; }
}

// ---------- fused LayerNorm (stats + apply), one block per row -------------
template<int SRC_F32>
__global__ __launch_bounds__(256) void ln_k(const void* __restrict__ src,
    const float* __restrict__ g, const float* __restrict__ b,
    unsigned short* __restrict__ out) {
  const int row = blockIdx.x, tid = threadIdx.x;
  const size_t base = (size_t)row * D_MODEL;
  float v[3];
  #pragma unroll
  for (int i = 0; i < 3; ++i) {
    const int c = tid + (i << 8);
    v[i] = SRC_F32 ? ((const float*)src)[base + c]
                   : bf2f(((const unsigned short*)src)[base + c]);
  }
  float s  = v[0] + v[1] + v[2];
  float sq = v[0]*v[0] + v[1]*v[1] + v[2]*v[2];
  #pragma unroll
  for (int m = 32; m; m >>= 1) { s += __shfl_xor(s, m); sq += __shfl_xor(sq, m); }
  __shared__ float ps[4], pq[4];
  if ((tid & 63) == 0) { ps[tid >> 6] = s; pq[tid >> 6] = sq; }
  __syncthreads();
  s  = ps[0] + ps[1] + ps[2] + ps[3];
  sq = pq[0] + pq[1] + pq[2] + pq[3];
  const float mu  = s * (1.0f / 768.0f);
  const float var = sq * (1.0f / 768.0f) - mu * mu;
  const float inv = rsqrtf(var + 1e-5f);
  #pragma unroll
  for (int i = 0; i < 3; ++i) {
    const int c = tid + (i << 8);
    out[base + c] = f2bf((v[i] - mu) * inv * g[c] + b[c]);
  }
}

// ---- GEMM: C[M,N] = A[M,K](bf16) @ Bt[N,K]^T(bf16) + bias(f32) ------------
// 2-phase pipeline (dbuf LDS, counted vmcnt, raw barriers), XCD swizzle,
// coalesced epilogue (per-wave LDS bounce -> 16B/lane stores).
// EP 0: bf16 store            | 1: gelu -> bf16
// EP 2: +resid(f32) -> bf16   | 3: gelu + resid(bf16) -> f32 (final output)
// EP 5: fused QKV split store (outv=q, residv=k, aux=v^T layout)
template<int EP>
__global__ __launch_bounds__(256) void gemm_k(
    const unsigned short* __restrict__ Au, const unsigned short* __restrict__ Btu,
    const float* __restrict__ bias, void* __restrict__ outv,
    const void* __restrict__ residv, void* __restrict__ aux,
    int M, int N, int K) {
  __shared__ __align__(16) __bf16 SMEM[2 * 2 * 128 * 32];   // 32 KB
  auto As = (__bf16 (*)[128][32])(SMEM);                    // As[buf][r][c]
  auto Bs = (__bf16 (*)[128][32])(SMEM + 2 * 128 * 32);     // Bs[buf][r][c]
  const __bf16* A  = (const __bf16*)Au;
  const __bf16* Bt = (const __bf16*)Btu;
  const int tid = threadIdx.x;
  const int lane = tid & 63, wid = tid >> 6;
  const int wr = wid >> 1, wc = wid & 1;
  // XCD-aware bijective remap (all grids have nwg % 8 == 0)
  const int gx = gridDim.x;
  const int nwg = gx * gridDim.y;
  int bid = blockIdx.y * gx + blockIdx.x;
  bid = (bid & 7) * (nwg >> 3) + (bid >> 3);
  const int brow = (bid % gx) * 128, bcol = (bid / gx) * 128;
  const int lr = lane & 15, lg = lane >> 4;
  f32x4 acc[4][4];
  #pragma unroll
  for (int m = 0; m < 4; ++m)
    #pragma unroll
    for (int n = 0; n < 4; ++n) acc[m][n] = (f32x4){0.f, 0.f, 0.f, 0.f};

  // per-wave staging: 32 A-rows + 32 B-rows, 16B per lane, linear LDS dest
  const int srow = (wid << 5) + (lane >> 2);
  const int scol = (lane & 3) << 3;
  const __bf16* gA = A  + (size_t)(brow + srow) * K + scol;
  const __bf16* gB = Bt + (size_t)(bcol + srow) * K + scol;

#define STAGE_(buf_, k0_) do {                                        \
    gload16(gA + (k0_),                   &As[buf_][(wid << 5)][0]);  \
    gload16(gA + (k0_) + 16 * (size_t)K,  &As[buf_][(wid << 5) + 16][0]); \
    gload16(gB + (k0_),                   &Bs[buf_][(wid << 5)][0]);  \
    gload16(gB + (k0_) + 16 * (size_t)K,  &Bs[buf_][(wid << 5) + 16][0]); \
  } while (0)

  STAGE_(0, 0);
  int cur = 0;
  for (int k0 = 0; k0 < K; k0 += 32, cur ^= 1) {
    if (k0 + 32 < K) {
      STAGE_(cur ^ 1, k0 + 32);
      asm volatile("s_waitcnt vmcnt(4)" ::: "memory");
    } else {
      asm volatile("s_waitcnt vmcnt(0)" ::: "memory");
    }
    __builtin_amdgcn_s_barrier();
    __builtin_amdgcn_sched_barrier(0);
    bf16x8 af[4], bfr[4];
    #pragma unroll
    for (int m = 0; m < 4; ++m) af[m]  = *(const bf16x8*)(&As[cur][wr*64 + m*16 + lr][lg*8]);
    #pragma unroll
    for (int n = 0; n < 4; ++n) bfr[n] = *(const bf16x8*)(&Bs[cur][wc*64 + n*16 + lr][lg*8]);
    #pragma unroll
    for (int m = 0; m < 4; ++m)
      #pragma unroll
      for (int n = 0; n < 4; ++n)
        acc[m][n] = __builtin_amdgcn_mfma_f32_16x16x32_bf16(af[m], bfr[n], acc[m][n], 0, 0, 0);
    asm volatile("s_waitcnt lgkmcnt(0)" ::: "memory");
    __builtin_amdgcn_sched_barrier(0);
    __builtin_amdgcn_s_barrier();
    __builtin_amdgcn_sched_barrier(0);
  }
#undef STAGE_

  const int seg = (EP == 5) ? (bcol / 768) : 0;     // block-uniform
  unsigned short* qkvp = nullptr;
  if (EP == 5)
    qkvp = (seg == 0) ? (unsigned short*)outv
         : (seg == 1) ? (unsigned short*)residv : (unsigned short*)aux;

  if (EP == 5 && seg == 2) {
    // v^T scatter store (per batch): vt[(b*768 + colL)*1024 + token]
    #pragma unroll
    for (int n = 0; n < 4; ++n) {
      const int col = bcol + wc*64 + n*16 + lr;
      const float bv = bias[col];
      const int colL = col - 1536;
      #pragma unroll
      for (int m = 0; m < 4; ++m) {
        const int row0 = brow + wr*64 + m*16 + lg*4;
        #pragma unroll
        for (int r = 0; r < 4; ++r) {
          const int gr = row0 + r;
          qkvp[(((size_t)(gr >> 10) * D_MODEL + colL) << 10) + (gr & 1023)] =
              f2bf(acc[m][n][r] + bv);
        }
      }
    }
  } else {
    // coalesced bounce: per-wave f32 tile [64 col][20 row] in SMEM (free now)
    float* Ep = (float*)SMEM + wid * 1280;   // 5120 B per wave
    #pragma unroll
    for (int p = 0; p < 4; ++p) {
      #pragma unroll
      for (int n = 0; n < 4; ++n) {
        const int col = bcol + wc*64 + n*16 + lr;
        const float bv = bias[col];
        f32x4 st;
        #pragma unroll
        for (int r = 0; r < 4; ++r) {
          float v = acc[p][n][r] + bv;
          if (EP == 1 || EP == 3) v = gelu_f(v);
          st[r] = v;
        }
        *(f32x4*)(Ep + (n*16 + lr) * 20 + lg*4) = st;   // 16B aligned
      }
      #pragma unroll
      for (int i2 = 0; i2 < 2; ++i2) {
        const int rowL = i2*8 + (lane >> 3);
        const int colL = (lane & 7) * 8;
        const int grow = brow + wr*64 + p*16 + rowL;
        const int gcol = bcol + wc*64 + colL;
        float v[8];
        #pragma unroll
        for (int j = 0; j < 8; ++j) v[j] = Ep[(colL + j) * 20 + rowL];
        const size_t o = (size_t)grow * N + gcol;
        if (EP == 3) {                 // + resid(bf16) -> f32 out
          const bf16x8 rv = *(const bf16x8*)((const __bf16*)residv + o);
          float* op = (float*)outv + o;
          float4 o0, o1;
          o0.x = v[0] + (float)rv[0]; o0.y = v[1] + (float)rv[1];
          o0.z = v[2] + (float)rv[2]; o0.w = v[3] + (float)rv[3];
          o1.x = v[4] + (float)rv[4]; o1.y = v[5] + (float)rv[5];
          o1.z = v[6] + (float)rv[6]; o1.w = v[7] + (float)rv[7];
          *(float4*)op = o0; *(float4*)(op + 4) = o1;
        } else if (EP == 2) {          // + resid(f32) -> bf16
          const float* rp = (const float*)residv + o;
          const float4 r0 = *(const float4*)rp, r1 = *(const float4*)(rp + 4);
          bf16x8 ov;
          ov[0] = (__bf16)(v[0] + r0.x); ov[1] = (__bf16)(v[1] + r0.y);
          ov[2] = (__bf16)(v[2] + r0.z); ov[3] = (__bf16)(v[3] + r0.w);
          ov[4] = (__bf16)(v[4] + r1.x); ov[5] = (__bf16)(v[5] + r1.y);
          ov[6] = (__bf16)(v[6] + r1.z); ov[7] = (__bf16)(v[7] + r1.w);
          *(bf16x8*)((__bf16*)outv + o) = ov;
        } else if (EP == 5) {          // q/k segment, 768-wide dest
          bf16x8 ov;
          #pragma unroll
          for (int j = 0; j < 8; ++j) ov[j] = (__bf16)v[j];
          *(bf16x8*)((__bf16*)qkvp + (size_t)grow * 768 + (gcol - seg * 768)) = ov;
        } else {                       // EP 0 / 1
          bf16x8 ov;
          #pragma unroll
          for (int j = 0; j < 8; ++j) ov[j] = (__bf16)v[j];
          *(bf16x8*)((__bf16*)outv + o) = ov;
        }
      }
    }
  }
}

// ---------------- flash attention: block = (b, h, 256 q-rows), 8 waves -----
__global__ __launch_bounds__(512) void attn_k(
    const unsigned short* qu, const unsigned short* __restrict__ ku,
    const unsigned short* __restrict__ vtu, unsigned short* attn) {
  __shared__ __align__(16) __bf16 Kl[64][72];
  __shared__ __align__(16) __bf16 Vl[64][72];
  __shared__ __align__(16) __bf16 Pl[8][16][72];
  const __bf16* qg  = (const __bf16*)qu;
  const __bf16* kg  = (const __bf16*)ku;
  const __bf16* vtg = (const __bf16*)vtu;
  const int bh = blockIdx.x, b = bh / 12, h = bh % 12;
  const int q0 = blockIdx.y * 256;
  const int tid = threadIdx.x, lane = tid & 63, w = tid >> 6;
  const int lr = lane & 15, lg = lane >> 4;
  const float scale = 0.03608439182435161f; // 1/sqrt(768)

  bf16x8 qa[2][2];
  #pragma unroll
  for (int g = 0; g < 2; ++g) {
    const int qrow = b * T_SEQ + q0 + w * 32 + g * 16 + lr;
    const __bf16* qp = qg + (size_t)qrow * D_MODEL + h * 64 + lg * 8;
    qa[g][0] = *(const bf16x8*)(qp);
    qa[g][1] = *(const bf16x8*)(qp + 32);
  }

  const __bf16* kb = kg  + (size_t)b * T_SEQ * D_MODEL + h * 64;
  const __bf16* vb = vtg + ((size_t)b * D_MODEL + h * 64) * T_SEQ;

  f32x4 o[2][4];
  float m_run[2] = {-1e30f, -1e30f}, l_run[2] = {0.f, 0.f};
  #pragma unroll
  for (int g = 0; g < 2; ++g)
    #pragma unroll
    for (int m = 0; m < 4; ++m) o[g][m] = (f32x4){0.f, 0.f, 0.f, 0.f};

  for (int kv0 = 0; kv0 < T_SEQ; kv0 += 64) {
    __syncthreads();
    {
      const int r = tid >> 3, c = (tid & 7) << 3;
      *(bf16x8*)(&Kl[r][c]) = *(const bf16x8*)(kb + (size_t)(kv0 + r) * D_MODEL + c);
      *(bf16x8*)(&Vl[r][c]) = *(const bf16x8*)(vb + (size_t)r * T_SEQ + kv0 + c);
    }
    __syncthreads();

    #pragma unroll
    for (int g = 0; g < 2; ++g) {
      f32x4 s[4];
      __builtin_amdgcn_s_setprio(1);
      #pragma unroll
      for (int m = 0; m < 4; ++m) {
        s[m] = (f32x4){0.f, 0.f, 0.f, 0.f};
        const bf16x8 kf0 = *(const bf16x8*)(&Kl[m*16 + lr][lg*8]);
        const bf16x8 kf1 = *(const bf16x8*)(&Kl[m*16 + lr][32 + lg*8]);
        s[m] = __builtin_amdgcn_mfma_f32_16x16x32_bf16(kf0, qa[g][0], s[m], 0, 0, 0);
        s[m] = __builtin_amdgcn_mfma_f32_16x16x32_bf16(kf1, qa[g][1], s[m], 0, 0, 0);
      }
      __builtin_amdgcn_s_setprio(0);
      float sv[4][4], tm = -1e30f;
      #pragma unroll
      for (int m = 0; m < 4; ++m)
        #pragma unroll
        for (int r = 0; r < 4; ++r) {
          sv[m][r] = s[m][r] * scale;
          tm = fmaxf(tm, sv[m][r]);
        }
      tm = fmaxf(tm, __shfl_xor(tm, 16));
      tm = fmaxf(tm, __shfl_xor(tm, 32));
      const float mn = fmaxf(m_run[g], tm);
      const float sc = __expf(m_run[g] - mn);
      float ts = 0.f;
      bf16x4 pk[4];
      #pragma unroll
      for (int m = 0; m < 4; ++m)
        #pragma unroll
        for (int r = 0; r < 4; ++r) {
          const float pp = __expf(sv[m][r] - mn);
          ts += pp;
          pk[m][r] = (__bf16)pp;
        }
      ts += __shfl_xor(ts, 16);
      ts += __shfl_xor(ts, 32);
      l_run[g] = l_run[g] * sc + ts;
      m_run[g] = mn;
      #pragma unroll
      for (int m = 0; m < 4; ++m)
        #pragma unroll
        for (int r = 0; r < 4; ++r) o[g][m][r] *= sc;
      #pragma unroll
      for (int m = 0; m < 4; ++m)
        *(bf16x4*)(&Pl[w][lr][16*m + 4*lg]) = pk[m];
      const bf16x8 pf0 = *(const bf16x8*)(&Pl[w][lr][lg*8]);
      const bf16x8 pf1 = *(const bf16x8*)(&Pl[w][lr][32 + lg*8]);
      __builtin_amdgcn_s_setprio(1);
      #pragma unroll
      for (int m = 0; m < 4; ++m) {
        const bf16x8 vf0 = *(const bf16x8*)(&Vl[m*16 + lr][lg*8]);
        const bf16x8 vf1 = *(const bf16x8*)(&Vl[m*16 + lr][32 + lg*8]);
        o[g][m] = __builtin_amdgcn_mfma_f32_16x16x32_bf16(vf0, pf0, o[g][m], 0, 0, 0);
        o[g][m] = __builtin_amdgcn_mfma_f32_16x16x32_bf16(vf1, pf1, o[g][m], 0, 0, 0);
      }
      __builtin_amdgcn_s_setprio(0);
    }
  }

  #pragma unroll
  for (int g = 0; g < 2; ++g) {
    const float inv = 1.0f / l_run[g];
    const int qrow = b * T_SEQ + q0 + w * 32 + g * 16 + lr;
    unsigned short* op = attn + (size_t)qrow * D_MODEL + h * 64;
    #pragma unroll
    for (int m = 0; m < 4; ++m) {
      bf16x4 ov;
      #pragma unroll
      for (int r = 0; r < 4; ++r) ov[r] = (__bf16)(o[g][m][r] * inv);
      *(bf16x4*)(op + 16*m + 4*lg) = ov;
    }
  }
}

// ---------------------------------------------------------------------------
extern "C" void kernel_launch(void* const* d_in, const int* in_sizes, int n_in,
                              void* d_out, int out_size, void* d_ws, size_t ws_size,
                              hipStream_t stream) {
  const float* x   = (const float*)d_in[0];
  const float* Wq  = (const float*)d_in[1];
  const float* bq  = (const float*)d_in[2];
  const float* Wk  = (const float*)d_in[3];
  const float* bk  = (const float*)d_in[4];
  const float* Wv  = (const float*)d_in[5];
  const float* bv  = (const float*)d_in[6];
  const float* Wo  = (const float*)d_in[7];
  const float* bo  = (const float*)d_in[8];
  const float* g1  = (const float*)d_in[9];
  const float* bt1 = (const float*)d_in[10];
  const float* g2  = (const float*)d_in[11];
  const float* bt2 = (const float*)d_in[12];
  const float* W1  = (const float*)d_in[13];
  const float* bb1 = (const float*)d_in[14];
  const float* W2  = (const float*)d_in[15];
  const float* bb2 = (const float*)d_in[16];

  // ws layout: [wqkvT][woT][w1T][w2T][bqkv][slot0: k->res2][hid region: vT -> hid]
  // hid region size decides MLP chunking (1/2/4) at runtime (deterministic).
  const size_t SZ = (size_t)M_ROWS * D_MODEL * 2;   // 25,165,824
  char* wp = (char*)d_ws;
  unsigned short* wqkvT = (unsigned short*)wp; wp += (size_t)2304 * 768 * 2;
  unsigned short* woT   = (unsigned short*)wp; wp += (size_t)768 * 768 * 2;
  unsigned short* w1T   = (unsigned short*)wp; wp += (size_t)768 * 3072 * 2;
  unsigned short* w2T   = (unsigned short*)wp; wp += (size_t)768 * 3072 * 2;
  float*          bqkv  = (float*)wp;          wp += ((size_t)2304 * 4 + 255) & ~(size_t)255;
  unsigned short* kbuf  = (unsigned short*)wp; wp += SZ;   // k -> res2
  unsigned short* vtb   = (unsigned short*)wp;             // vT -> hid
  unsigned short* res2  = kbuf;
  unsigned short* hid   = vtb;
  const size_t avail = ws_size - (size_t)(wp - (char*)d_ws);
  const int nch = (avail >= (size_t)M_ROWS * MLP_DIM * 2) ? 1
                : (avail >= (size_t)(M_ROWS / 2) * MLP_DIM * 2) ? 2 : 4;

  unsigned short* qd = (unsigned short*)d_out;             // bf16 lo half
  unsigned short* h1 = qd + (size_t)M_ROWS * D_MODEL;      // bf16 hi half
  unsigned short* h2 = h1;

  const dim3 tb(32, 8, 1);
  wtr_k<<<dim3(24, 24), tb, 0, stream>>>(Wq, wqkvT, 768, 768);
  wtr_k<<<dim3(24, 24), tb, 0, stream>>>(Wk, wqkvT + (size_t)768 * 768, 768, 768);
  wtr_k<<<dim3(24, 24), tb, 0, stream>>>(Wv, wqkvT + (size_t)1536 * 768, 768, 768);
  wtr_k<<<dim3(24, 24), tb, 0, stream>>>(Wo, woT, 768, 768);
  wtr_k<<<dim3(96, 24), tb, 0, stream>>>(W1, w1T, 768, 3072);
  wtr_k<<<dim3(24, 96), tb, 0, stream>>>(W2, w2T, 3072, 768);
  bcat_k<<<3, 256, 0, stream>>>(bq, bk, bv, bqkv);

  ln_k<1><<<M_ROWS, 256, 0, stream>>>(x, g1, bt1, h1);

  gemm_k<5><<<dim3(128, 18), 256, 0, stream>>>(h1, wqkvT, bqkv, qd, kbuf, vtb,
                                               M_ROWS, 2304, 768);

  attn_k<<<dim3(192, 4), 512, 0, stream>>>(qd, kbuf, vtb, qd);

  gemm_k<2><<<dim3(128, 6), 256, 0, stream>>>(qd, woT, bo, res2, x, nullptr,
                                              M_ROWS, 768, 768);

  ln_k<0><<<M_ROWS, 256, 0, stream>>>(res2, g2, bt2, h2);

  const int CH = M_ROWS / nch;
  for (int c = 0; c < nch; ++c) {
    const size_t ro = (size_t)c * CH;
    gemm_k<1><<<dim3(CH / 128, 24), 256, 0, stream>>>(h2 + ro * 768, w1T, bb1, hid,
        nullptr, nullptr, CH, 3072, 768);
    gemm_k<3><<<dim3(CH / 128, 6), 256, 0, stream>>>(hid, w2T, bb2,
        (float*)d_out + ro * 768, res2 + ro * 768, nullptr, CH, 768, 3072);
  }
}

// Round 10
// 537.279 us; speedup vs baseline: 4.5381x; 1.0015x over previous
//
#include <hip/hip_runtime.h>
#include <hip/hip_bf16.h>
#include <math.h>

#define D_MODEL 768
#define T_SEQ   1024
#define B_BATCH 16
#define MLP_DIM 3072
#define M_ROWS  (B_BATCH * T_SEQ)   // 16384

typedef __attribute__((ext_vector_type(8))) __bf16          bf16x8;
typedef __attribute__((ext_vector_type(4))) __bf16          bf16x4;
typedef __attribute__((ext_vector_type(4))) float           f32x4;

__device__ __forceinline__ float bf2f(unsigned short u) {
  union { unsigned int u; float f; } w; w.u = ((unsigned int)u) << 16; return w.f;
}
__device__ __forceinline__ unsigned short f2bf(float f) {
  union { float f; unsigned int u; } w; w.f = f;
  unsigned int r = (w.u + 0x7fffu + ((w.u >> 16) & 1u)) >> 16;
  return (unsigned short)r;
}
__device__ __forceinline__ float gelu_f(float x) {
  return 0.5f * x * (1.0f + erff(x * 0.70710678118654752f));
}
// async global->LDS, 16B per lane; LDS dest = wave-uniform base + lane*16
__device__ __forceinline__ void gload16(const void* g, void* l) {
  __builtin_amdgcn_global_load_lds(
      (const __attribute__((address_space(1))) unsigned int*)g,
      (__attribute__((address_space(3))) unsigned int*)l, 16, 0, 0);
}

// ------- weight transpose+convert: dst[N=C][K=R] bf16 = src[R][C] f32 ------
__global__ void wtr_k(const float* __restrict__ src,
                      unsigned short* __restrict__ dst, int R, int C) {
  __shared__ float t[32][33];
  const int c0 = blockIdx.x * 32, r0 = blockIdx.y * 32;
  const int tx = threadIdx.x, ty = threadIdx.y;
  #pragma unroll
  for (int j = 0; j < 32; j += 8)
    t[ty + j][tx] = src[(size_t)(r0 + ty + j) * C + (c0 + tx)];
  __syncthreads();
  #pragma unroll
  for (int j = 0; j < 32; j += 8)
    dst[(size_t)(c0 + ty + j) * R + (r0 + tx)] = f2bf(t[tx][ty + j]);
}

// ------- concat 3 bias vectors of 768 f32 --------------------------------
__global__ void bcat_k(const float* __restrict__ a, const float* __restrict__ b,
                       const float* __restrict__ c, float* __restrict__ o) {
  const int i = blockIdx.x * 256 + threadIdx.x;
  if (i < 768) { o[i] = a[i]; o[i + 768] = b[i]; o[i + 1536] = c[i]; }
}

// ---------- fused LayerNorm (stats + apply), one block per row -------------
template<int SRC_F32>
__global__ __launch_bounds__(256) void ln_k(const void* __restrict__ src,
    const float* __restrict__ g, const float* __restrict__ b,
    unsigned short* __restrict__ out) {
  const int row = blockIdx.x, tid = threadIdx.x;
  const size_t base = (size_t)row * D_MODEL;
  float v[3];
  #pragma unroll
  for (int i = 0; i < 3; ++i) {
    const int c = tid + (i << 8);
    v[i] = SRC_F32 ? ((const float*)src)[base + c]
                   : bf2f(((const unsigned short*)src)[base + c]);
  }
  float s  = v[0] + v[1] + v[2];
  float sq = v[0]*v[0] + v[1]*v[1] + v[2]*v[2];
  #pragma unroll
  for (int m = 32; m; m >>= 1) { s += __shfl_xor(s, m); sq += __shfl_xor(sq, m); }
  __shared__ float ps[4], pq[4];
  if ((tid & 63) == 0) { ps[tid >> 6] = s; pq[tid >> 6] = sq; }
  __syncthreads();
  s  = ps[0] + ps[1] + ps[2] + ps[3];
  sq = pq[0] + pq[1] + pq[2] + pq[3];
  const float mu  = s * (1.0f / 768.0f);
  const float var = sq * (1.0f / 768.0f) - mu * mu;
  const float inv = rsqrtf(var + 1e-5f);
  #pragma unroll
  for (int i = 0; i < 3; ++i) {
    const int c = tid + (i << 8);
    out[base + c] = f2bf((v[i] - mu) * inv * g[c] + b[c]);
  }
}

// ---- GEMM: C[M,N] = A[M,K](bf16) @ Bt[N,K]^T(bf16) + bias(f32) ------------
// 2-phase pipeline (dbuf LDS, counted vmcnt, raw barriers).
// Block mapping: XCD owns a row-stripe, col-fastest within XCD -> B panel
// L2-resident per XCD after first sweep; A-stripe read ~once per XCD.
// cb = column base (Bt pre-offset by caller; bias/out use global col).
// EP 0: bf16 store            | 1: gelu -> bf16
// EP 2: +resid(f32) -> bf16   | 3: gelu + resid(bf16) -> f32 (final output)
// EP 5: fused QKV split store (outv=q, residv=k, aux=v^T layout)
template<int EP>
__global__ __launch_bounds__(256) void gemm_k(
    const unsigned short* __restrict__ Au, const unsigned short* __restrict__ Btu,
    const float* __restrict__ bias, void* __restrict__ outv,
    const void* __restrict__ residv, void* __restrict__ aux,
    int M, int N, int K, int cb) {
  __shared__ __align__(16) __bf16 SMEM[2 * 2 * 128 * 32];   // 32 KB
  auto As = (__bf16 (*)[128][32])(SMEM);
  auto Bs = (__bf16 (*)[128][32])(SMEM + 2 * 128 * 32);
  const __bf16* A  = (const __bf16*)Au;
  const __bf16* Bt = (const __bf16*)Btu;
  const int tid = threadIdx.x;
  const int lane = tid & 63, wid = tid >> 6;
  const int wr = wid >> 1, wc = wid & 1;
  // XCD row-stripe, col-fastest (requires gridDim.x % 8 == 0)
  const int gx = gridDim.x, gy = gridDim.y;
  const int bid = blockIdx.y * gx + blockIdx.x;
  const int xcd = bid & 7, idx = bid >> 3;
  const int rpx = gx >> 3;
  const int brow  = (xcd * rpx + idx / gy) * 128;
  const int bcolL = (idx % gy) * 128;           // local col (Bt space)
  const int bcol  = cb + bcolL;                 // global col (bias/out space)
  const int lr = lane & 15, lg = lane >> 4;
  f32x4 acc[4][4];
  #pragma unroll
  for (int m = 0; m < 4; ++m)
    #pragma unroll
    for (int n = 0; n < 4; ++n) acc[m][n] = (f32x4){0.f, 0.f, 0.f, 0.f};

  const int srow = (wid << 5) + (lane >> 2);
  const int scol = (lane & 3) << 3;
  const __bf16* gA = A  + (size_t)(brow  + srow) * K + scol;
  const __bf16* gB = Bt + (size_t)(bcolL + srow) * K + scol;

#define STAGE_(buf_, k0_) do {                                        \
    gload16(gA + (k0_),                   &As[buf_][(wid << 5)][0]);  \
    gload16(gA + (k0_) + 16 * (size_t)K,  &As[buf_][(wid << 5) + 16][0]); \
    gload16(gB + (k0_),                   &Bs[buf_][(wid << 5)][0]);  \
    gload16(gB + (k0_) + 16 * (size_t)K,  &Bs[buf_][(wid << 5) + 16][0]); \
  } while (0)

  STAGE_(0, 0);
  int cur = 0;
  for (int k0 = 0; k0 < K; k0 += 32, cur ^= 1) {
    if (k0 + 32 < K) {
      STAGE_(cur ^ 1, k0 + 32);
      asm volatile("s_waitcnt vmcnt(4)" ::: "memory");
    } else {
      asm volatile("s_waitcnt vmcnt(0)" ::: "memory");
    }
    __builtin_amdgcn_s_barrier();
    __builtin_amdgcn_sched_barrier(0);
    bf16x8 af[4], bfr[4];
    #pragma unroll
    for (int m = 0; m < 4; ++m) af[m]  = *(const bf16x8*)(&As[cur][wr*64 + m*16 + lr][lg*8]);
    #pragma unroll
    for (int n = 0; n < 4; ++n) bfr[n] = *(const bf16x8*)(&Bs[cur][wc*64 + n*16 + lr][lg*8]);
    #pragma unroll
    for (int m = 0; m < 4; ++m)
      #pragma unroll
      for (int n = 0; n < 4; ++n)
        acc[m][n] = __builtin_amdgcn_mfma_f32_16x16x32_bf16(af[m], bfr[n], acc[m][n], 0, 0, 0);
    asm volatile("s_waitcnt lgkmcnt(0)" ::: "memory");
    __builtin_amdgcn_sched_barrier(0);
    __builtin_amdgcn_s_barrier();
    __builtin_amdgcn_sched_barrier(0);
  }
#undef STAGE_

  const int seg = (EP == 5) ? (bcol / 768) : 0;     // block-uniform
  unsigned short* qkvp = nullptr;
  if (EP == 5)
    qkvp = (seg == 0) ? (unsigned short*)outv
         : (seg == 1) ? (unsigned short*)residv : (unsigned short*)aux;

  if (EP == 5 && seg == 2) {
    // v^T scatter store (per batch): vt[(b*768 + colLv)*1024 + token]
    #pragma unroll
    for (int n = 0; n < 4; ++n) {
      const int col = bcol + wc*64 + n*16 + lr;
      const float bv = bias[col];
      const int colLv = col - 1536;
      #pragma unroll
      for (int m = 0; m < 4; ++m) {
        const int row0 = brow + wr*64 + m*16 + lg*4;
        #pragma unroll
        for (int r = 0; r < 4; ++r) {
          const int gr = row0 + r;
          qkvp[(((size_t)(gr >> 10) * D_MODEL + colLv) << 10) + (gr & 1023)] =
              f2bf(acc[m][n][r] + bv);
        }
      }
    }
  } else {
    // coalesced bounce: per-wave f32 tile [64 col][20 row] in SMEM (free now)
    float* Ep = (float*)SMEM + wid * 1280;
    #pragma unroll
    for (int p = 0; p < 4; ++p) {
      #pragma unroll
      for (int n = 0; n < 4; ++n) {
        const int col = bcol + wc*64 + n*16 + lr;
        const float bv = bias[col];
        f32x4 st;
        #pragma unroll
        for (int r = 0; r < 4; ++r) {
          float v = acc[p][n][r] + bv;
          if (EP == 1 || EP == 3) v = gelu_f(v);
          st[r] = v;
        }
        *(f32x4*)(Ep + (n*16 + lr) * 20 + lg*4) = st;
      }
      #pragma unroll
      for (int i2 = 0; i2 < 2; ++i2) {
        const int rowL = i2*8 + (lane >> 3);
        const int colL = (lane & 7) * 8;
        const int grow = brow + wr*64 + p*16 + rowL;
        const int gcol = bcol + wc*64 + colL;
        float v[8];
        #pragma unroll
        for (int j = 0; j < 8; ++j) v[j] = Ep[(colL + j) * 20 + rowL];
        const size_t o = (size_t)grow * N + gcol;
        if (EP == 3) {
          const bf16x8 rv = *(const bf16x8*)((const __bf16*)residv + o);
          float* op = (float*)outv + o;
          float4 o0, o1;
          o0.x = v[0] + (float)rv[0]; o0.y = v[1] + (float)rv[1];
          o0.z = v[2] + (float)rv[2]; o0.w = v[3] + (float)rv[3];
          o1.x = v[4] + (float)rv[4]; o1.y = v[5] + (float)rv[5];
          o1.z = v[6] + (float)rv[6]; o1.w = v[7] + (float)rv[7];
          *(float4*)op = o0; *(float4*)(op + 4) = o1;
        } else if (EP == 2) {
          const float* rp = (const float*)residv + o;
          const float4 r0 = *(const float4*)rp, r1 = *(const float4*)(rp + 4);
          bf16x8 ov;
          ov[0] = (__bf16)(v[0] + r0.x); ov[1] = (__bf16)(v[1] + r0.y);
          ov[2] = (__bf16)(v[2] + r0.z); ov[3] = (__bf16)(v[3] + r0.w);
          ov[4] = (__bf16)(v[4] + r1.x); ov[5] = (__bf16)(v[5] + r1.y);
          ov[6] = (__bf16)(v[6] + r1.z); ov[7] = (__bf16)(v[7] + r1.w);
          *(bf16x8*)((__bf16*)outv + o) = ov;
        } else if (EP == 5) {          // q/k segment, 768-wide dest
          bf16x8 ov;
          #pragma unroll
          for (int j = 0; j < 8; ++j) ov[j] = (__bf16)v[j];
          *(bf16x8*)((__bf16*)qkvp + (size_t)grow * 768 + (gcol - seg * 768)) = ov;
        } else {                       // EP 0 / 1
          bf16x8 ov;
          #pragma unroll
          for (int j = 0; j < 8; ++j) ov[j] = (__bf16)v[j];
          *(bf16x8*)((__bf16*)outv + o) = ov;
        }
      }
    }
  }
}

// ---------------- flash attention: 768 blocks, XCD-sequential bh -----------
// bid -> xcd=bid&7, idx=bid>>3: bh = xcd*24 + idx/4, q0 = (idx&3)*256.
// All 4 q-chunks of a (b,h) run back-to-back on one XCD -> K/V L2-resident.
__global__ __launch_bounds__(512) void attn_k(
    const unsigned short* qu, const unsigned short* __restrict__ ku,
    const unsigned short* __restrict__ vtu, unsigned short* attn) {
  __shared__ __align__(16) __bf16 Kl[64][72];
  __shared__ __align__(16) __bf16 Vl[64][72];
  __shared__ __align__(16) __bf16 Pl[8][16][72];
  const __bf16* qg  = (const __bf16*)qu;
  const __bf16* kg  = (const __bf16*)ku;
  const __bf16* vtg = (const __bf16*)vtu;
  const int bid = blockIdx.x;
  const int xcd = bid & 7, idx = bid >> 3;
  const int bh = xcd * 24 + (idx >> 2);
  const int b = bh / 12, h = bh % 12;
  const int q0 = (idx & 3) * 256;
  const int tid = threadIdx.x, lane = tid & 63, w = tid >> 6;
  const int lr = lane & 15, lg = lane >> 4;
  const float scale = 0.03608439182435161f; // 1/sqrt(768)

  bf16x8 qa[2][2];
  #pragma unroll
  for (int g = 0; g < 2; ++g) {
    const int qrow = b * T_SEQ + q0 + w * 32 + g * 16 + lr;
    const __bf16* qp = qg + (size_t)qrow * D_MODEL + h * 64 + lg * 8;
    qa[g][0] = *(const bf16x8*)(qp);
    qa[g][1] = *(const bf16x8*)(qp + 32);
  }

  const __bf16* kb = kg  + (size_t)b * T_SEQ * D_MODEL + h * 64;
  const __bf16* vb = vtg + ((size_t)b * D_MODEL + h * 64) * T_SEQ;

  f32x4 o[2][4];
  float m_run[2] = {-1e30f, -1e30f}, l_run[2] = {0.f, 0.f};
  #pragma unroll
  for (int g = 0; g < 2; ++g)
    #pragma unroll
    for (int m = 0; m < 4; ++m) o[g][m] = (f32x4){0.f, 0.f, 0.f, 0.f};

  for (int kv0 = 0; kv0 < T_SEQ; kv0 += 64) {
    __syncthreads();
    {
      const int r = tid >> 3, c = (tid & 7) << 3;
      *(bf16x8*)(&Kl[r][c]) = *(const bf16x8*)(kb + (size_t)(kv0 + r) * D_MODEL + c);
      *(bf16x8*)(&Vl[r][c]) = *(const bf16x8*)(vb + (size_t)r * T_SEQ + kv0 + c);
    }
    __syncthreads();

    #pragma unroll
    for (int g = 0; g < 2; ++g) {
      f32x4 s[4];
      __builtin_amdgcn_s_setprio(1);
      #pragma unroll
      for (int m = 0; m < 4; ++m) {
        s[m] = (f32x4){0.f, 0.f, 0.f, 0.f};
        const bf16x8 kf0 = *(const bf16x8*)(&Kl[m*16 + lr][lg*8]);
        const bf16x8 kf1 = *(const bf16x8*)(&Kl[m*16 + lr][32 + lg*8]);
        s[m] = __builtin_amdgcn_mfma_f32_16x16x32_bf16(kf0, qa[g][0], s[m], 0, 0, 0);
        s[m] = __builtin_amdgcn_mfma_f32_16x16x32_bf16(kf1, qa[g][1], s[m], 0, 0, 0);
      }
      __builtin_amdgcn_s_setprio(0);
      float sv[4][4], tm = -1e30f;
      #pragma unroll
      for (int m = 0; m < 4; ++m)
        #pragma unroll
        for (int r = 0; r < 4; ++r) {
          sv[m][r] = s[m][r] * scale;
          tm = fmaxf(tm, sv[m][r]);
        }
      tm = fmaxf(tm, __shfl_xor(tm, 16));
      tm = fmaxf(tm, __shfl_xor(tm, 32));
      const float mn = fmaxf(m_run[g], tm);
      const float sc = __expf(m_run[g] - mn);
      float ts = 0.f;
      bf16x4 pk[4];
      #pragma unroll
      for (int m = 0; m < 4; ++m)
        #pragma unroll
        for (int r = 0; r < 4; ++r) {
          const float pp = __expf(sv[m][r] - mn);
          ts += pp;
          pk[m][r] = (__bf16)pp;
        }
      ts += __shfl_xor(ts, 16);
      ts += __shfl_xor(ts, 32);
      l_run[g] = l_run[g] * sc + ts;
      m_run[g] = mn;
      #pragma unroll
      for (int m = 0; m < 4; ++m)
        #pragma unroll
        for (int r = 0; r < 4; ++r) o[g][m][r] *= sc;
      #pragma unroll
      for (int m = 0; m < 4; ++m)
        *(bf16x4*)(&Pl[w][lr][16*m + 4*lg]) = pk[m];
      const bf16x8 pf0 = *(const bf16x8*)(&Pl[w][lr][lg*8]);
      const bf16x8 pf1 = *(const bf16x8*)(&Pl[w][lr][32 + lg*8]);
      __builtin_amdgcn_s_setprio(1);
      #pragma unroll
      for (int m = 0; m < 4; ++m) {
        const bf16x8 vf0 = *(const bf16x8*)(&Vl[m*16 + lr][lg*8]);
        const bf16x8 vf1 = *(const bf16x8*)(&Vl[m*16 + lr][32 + lg*8]);
        o[g][m] = __builtin_amdgcn_mfma_f32_16x16x32_bf16(vf0, pf0, o[g][m], 0, 0, 0);
        o[g][m] = __builtin_amdgcn_mfma_f32_16x16x32_bf16(vf1, pf1, o[g][m], 0, 0, 0);
      }
      __builtin_amdgcn_s_setprio(0);
    }
  }

  #pragma unroll
  for (int g = 0; g < 2; ++g) {
    const float inv = 1.0f / l_run[g];
    const int qrow = b * T_SEQ + q0 + w * 32 + g * 16 + lr;
    unsigned short* op = attn + (size_t)qrow * D_MODEL + h * 64;
    #pragma unroll
    for (int m = 0; m < 4; ++m) {
      bf16x4 ov;
      #pragma unroll
      for (int r = 0; r < 4; ++r) ov[r] = (__bf16)(o[g][m][r] * inv);
      *(bf16x4*)(op + 16*m + 4*lg) = ov;
    }
  }
}

// ---------------------------------------------------------------------------
extern "C" void kernel_launch(void* const* d_in, const int* in_sizes, int n_in,
                              void* d_out, int out_size, void* d_ws, size_t ws_size,
                              hipStream_t stream) {
  const float* x   = (const float*)d_in[0];
  const float* Wq  = (const float*)d_in[1];
  const float* bq  = (const float*)d_in[2];
  const float* Wk  = (const float*)d_in[3];
  const float* bk  = (const float*)d_in[4];
  const float* Wv  = (const float*)d_in[5];
  const float* bv  = (const float*)d_in[6];
  const float* Wo  = (const float*)d_in[7];
  const float* bo  = (const float*)d_in[8];
  const float* g1  = (const float*)d_in[9];
  const float* bt1 = (const float*)d_in[10];
  const float* g2  = (const float*)d_in[11];
  const float* bt2 = (const float*)d_in[12];
  const float* W1  = (const float*)d_in[13];
  const float* bb1 = (const float*)d_in[14];
  const float* W2  = (const float*)d_in[15];
  const float* bb2 = (const float*)d_in[16];

  const size_t SZ = (size_t)M_ROWS * D_MODEL * 2;   // 25,165,824
  char* wp = (char*)d_ws;
  unsigned short* wqkvT = (unsigned short*)wp; wp += (size_t)2304 * 768 * 2;
  unsigned short* woT   = (unsigned short*)wp; wp += (size_t)768 * 768 * 2;
  unsigned short* w1T   = (unsigned short*)wp; wp += (size_t)768 * 3072 * 2;
  unsigned short* w2T   = (unsigned short*)wp; wp += (size_t)768 * 3072 * 2;
  float*          bqkv  = (float*)wp;          wp += ((size_t)2304 * 4 + 255) & ~(size_t)255;
  unsigned short* kbuf  = (unsigned short*)wp; wp += SZ;   // k -> res2
  unsigned short* vtb   = (unsigned short*)wp;             // vT -> hid
  unsigned short* res2  = kbuf;
  unsigned short* hid   = vtb;
  const size_t avail = ws_size - (size_t)(wp - (char*)d_ws);
  const int nch = (avail >= (size_t)M_ROWS * MLP_DIM * 2) ? 1
                : (avail >= (size_t)(M_ROWS / 2) * MLP_DIM * 2) ? 2 : 4;

  unsigned short* qd = (unsigned short*)d_out;             // bf16 lo half
  unsigned short* h1 = qd + (size_t)M_ROWS * D_MODEL;      // bf16 hi half
  unsigned short* h2 = h1;

  const dim3 tb(32, 8, 1);
  wtr_k<<<dim3(24, 24), tb, 0, stream>>>(Wq, wqkvT, 768, 768);
  wtr_k<<<dim3(24, 24), tb, 0, stream>>>(Wk, wqkvT + (size_t)768 * 768, 768, 768);
  wtr_k<<<dim3(24, 24), tb, 0, stream>>>(Wv, wqkvT + (size_t)1536 * 768, 768, 768);
  wtr_k<<<dim3(24, 24), tb, 0, stream>>>(Wo, woT, 768, 768);
  wtr_k<<<dim3(96, 24), tb, 0, stream>>>(W1, w1T, 768, 3072);
  wtr_k<<<dim3(24, 96), tb, 0, stream>>>(W2, w2T, 3072, 768);
  bcat_k<<<3, 256, 0, stream>>>(bq, bk, bv, bqkv);

  ln_k<1><<<M_ROWS, 256, 0, stream>>>(x, g1, bt1, h1);

  gemm_k<5><<<dim3(128, 18), 256, 0, stream>>>(h1, wqkvT, bqkv, qd, kbuf, vtb,
                                               M_ROWS, 2304, 768, 0);

  attn_k<<<dim3(768), 512, 0, stream>>>(qd, kbuf, vtb, qd);

  gemm_k<2><<<dim3(128, 6), 256, 0, stream>>>(qd, woT, bo, res2, x, nullptr,
                                              M_ROWS, 768, 768, 0);

  ln_k<0><<<M_ROWS, 256, 0, stream>>>(res2, g2, bt2, h2);

  const int CH = M_ROWS / nch;
  for (int c = 0; c < nch; ++c) {
    const size_t ro = (size_t)c * CH;
    // MLP1 in two column halves so each B-half (2.36 MB) is L2-resident
    for (int hh = 0; hh < 2; ++hh) {
      const int cbase = hh * 1536;
      gemm_k<1><<<dim3(CH / 128, 12), 256, 0, stream>>>(h2 + ro * 768,
          w1T + (size_t)cbase * 768, bb1, hid, nullptr, nullptr,
          CH, 3072, 768, cbase);
    }
    gemm_k<3><<<dim3(CH / 128, 6), 256, 0, stream>>>(hid, w2T, bb2,
        (float*)d_out + ro * 768, res2 + ro * 768, nullptr, CH, 768, 3072, 0);
  }
}

// Round 11
// 522.709 us; speedup vs baseline: 4.6646x; 1.0279x over previous
//
#include <hip/hip_runtime.h>
#include <hip/hip_bf16.h>
#include <math.h>

#define D_MODEL 768
#define T_SEQ   1024
#define B_BATCH 16
#define MLP_DIM 3072
#define M_ROWS  (B_BATCH * T_SEQ)   // 16384

typedef __attribute__((ext_vector_type(8))) __bf16          bf16x8;
typedef __attribute__((ext_vector_type(4))) __bf16          bf16x4;
typedef __attribute__((ext_vector_type(4))) float           f32x4;

__device__ __forceinline__ float bf2f(unsigned short u) {
  union { unsigned int u; float f; } w; w.u = ((unsigned int)u) << 16; return w.f;
}
__device__ __forceinline__ unsigned short f2bf(float f) {
  union { float f; unsigned int u; } w; w.f = f;
  unsigned int r = (w.u + 0x7fffu + ((w.u >> 16) & 1u)) >> 16;
  return (unsigned short)r;
}
__device__ __forceinline__ float gelu_f(float x) {
  return 0.5f * x * (1.0f + erff(x * 0.70710678118654752f));
}
// async global->LDS, 16B per lane; LDS dest = wave-uniform base + lane*16
__device__ __forceinline__ void gload16(const void* g, void* l) {
  __builtin_amdgcn_global_load_lds(
      (const __attribute__((address_space(1))) unsigned int*)g,
      (__attribute__((address_space(3))) unsigned int*)l, 16, 0, 0);
}

// ------- weight transpose+convert: dst[N=C][K=R] bf16 = src[R][C] f32 ------
__global__ void wtr_k(const float* __restrict__ src,
                      unsigned short* __restrict__ dst, int R, int C) {
  __shared__ float t[32][33];
  const int c0 = blockIdx.x * 32, r0 = blockIdx.y * 32;
  const int tx = threadIdx.x, ty = threadIdx.y;
  #pragma unroll
  for (int j = 0; j < 32; j += 8)
    t[ty + j][tx] = src[(size_t)(r0 + ty + j) * C + (c0 + tx)];
  __syncthreads();
  #pragma unroll
  for (int j = 0; j < 32; j += 8)
    dst[(size_t)(c0 + ty + j) * R + (r0 + tx)] = f2bf(t[tx][ty + j]);
}

// ------- concat 3 bias vectors of 768 f32 --------------------------------
__global__ void bcat_k(const float* __restrict__ a, const float* __restrict__ b,
                       const float* __restrict__ c, float* __restrict__ o) {
  const int i = blockIdx.x * 256 + threadIdx.x;
  if (i < 768) { o[i] = a[i]; o[i + 768] = b[i]; o[i + 1536] = c[i]; }
}

// ---------- fused LayerNorm (stats + apply), one block per row -------------
template<int SRC_F32>
__global__ __launch_bounds__(256) void ln_k(const void* __restrict__ src,
    const float* __restrict__ g, const float* __restrict__ b,
    unsigned short* __restrict__ out) {
  const int row = blockIdx.x, tid = threadIdx.x;
  const size_t base = (size_t)row * D_MODEL;
  float v[3];
  #pragma unroll
  for (int i = 0; i < 3; ++i) {
    const int c = tid + (i << 8);
    v[i] = SRC_F32 ? ((const float*)src)[base + c]
                   : bf2f(((const unsigned short*)src)[base + c]);
  }
  float s  = v[0] + v[1] + v[2];
  float sq = v[0]*v[0] + v[1]*v[1] + v[2]*v[2];
  #pragma unroll
  for (int m = 32; m; m >>= 1) { s += __shfl_xor(s, m); sq += __shfl_xor(sq, m); }
  __shared__ float ps[4], pq[4];
  if ((tid & 63) == 0) { ps[tid >> 6] = s; pq[tid >> 6] = sq; }
  __syncthreads();
  s  = ps[0] + ps[1] + ps[2] + ps[3];
  sq = pq[0] + pq[1] + pq[2] + pq[3];
  const float mu  = s * (1.0f / 768.0f);
  const float var = sq * (1.0f / 768.0f) - mu * mu;
  const float inv = rsqrtf(var + 1e-5f);
  #pragma unroll
  for (int i = 0; i < 3; ++i) {
    const int c = tid + (i << 8);
    out[base + c] = f2bf((v[i] - mu) * inv * g[c] + b[c]);
  }
}

// ---- GEMM: C[M,N] = A[M,K](bf16) @ Bt[N,K]^T(bf16) + bias(f32) ------------
// 2-phase pipeline (dbuf LDS, counted vmcnt, raw barriers).
// Block map: XCD owns a row-stripe; within an XCD, cols advance in groups of
// cgrp blocks (B-group <= ~2.4MB stays L2-resident), rows fastest in a group.
// cb = column base (Bt pre-offset by caller; bias/out use global col).
// EP 0: bf16 store            | 1: gelu -> bf16
// EP 2: +resid(f32) -> bf16   | 3: gelu + resid(bf16) -> f32 (final output)
// EP 5: fused QKV split store (outv=q, residv=k, aux=v^T layout)
template<int EP>
__global__ __launch_bounds__(256) void gemm_k(
    const unsigned short* __restrict__ Au, const unsigned short* __restrict__ Btu,
    const float* __restrict__ bias, void* __restrict__ outv,
    const void* __restrict__ residv, void* __restrict__ aux,
    int M, int N, int K, int cb, int cgrp) {
  __shared__ __align__(16) __bf16 SMEM[2 * 2 * 128 * 32];   // 32 KB
  auto As = (__bf16 (*)[128][32])(SMEM);
  auto Bs = (__bf16 (*)[128][32])(SMEM + 2 * 128 * 32);
  const __bf16* A  = (const __bf16*)Au;
  const __bf16* Bt = (const __bf16*)Btu;
  const int tid = threadIdx.x;
  const int lane = tid & 63, wid = tid >> 6;
  const int wr = wid >> 1, wc = wid & 1;
  // XCD row-stripe + col-group mapping (requires gridDim.x % 8 == 0,
  // gridDim.y % cgrp == 0)
  const int gx = gridDim.x, gy = gridDim.y;
  const int bid = blockIdx.y * gx + blockIdx.x;
  const int xcd = bid & 7, idx = bid >> 3;
  const int rpx = gx >> 3;
  const int gsz = rpx * cgrp;
  const int grp = idx / gsz, rem = idx - grp * gsz;
  const int r = rem / cgrp, c = rem - r * cgrp + grp * cgrp;
  const int brow  = (xcd * rpx + r) * 128;
  const int bcolL = c * 128;                    // local col (Bt space)
  const int bcol  = cb + bcolL;                 // global col (bias/out space)
  const int lr = lane & 15, lg = lane >> 4;
  f32x4 acc[4][4];
  #pragma unroll
  for (int m = 0; m < 4; ++m)
    #pragma unroll
    for (int n = 0; n < 4; ++n) acc[m][n] = (f32x4){0.f, 0.f, 0.f, 0.f};

  const int srow = (wid << 5) + (lane >> 2);
  const int scol = (lane & 3) << 3;
  const __bf16* gA = A  + (size_t)(brow  + srow) * K + scol;
  const __bf16* gB = Bt + (size_t)(bcolL + srow) * K + scol;

#define STAGE_(buf_, k0_) do {                                        \
    gload16(gA + (k0_),                   &As[buf_][(wid << 5)][0]);  \
    gload16(gA + (k0_) + 16 * (size_t)K,  &As[buf_][(wid << 5) + 16][0]); \
    gload16(gB + (k0_),                   &Bs[buf_][(wid << 5)][0]);  \
    gload16(gB + (k0_) + 16 * (size_t)K,  &Bs[buf_][(wid << 5) + 16][0]); \
  } while (0)

  STAGE_(0, 0);
  int cur = 0;
  for (int k0 = 0; k0 < K; k0 += 32, cur ^= 1) {
    if (k0 + 32 < K) {
      STAGE_(cur ^ 1, k0 + 32);
      asm volatile("s_waitcnt vmcnt(4)" ::: "memory");
    } else {
      asm volatile("s_waitcnt vmcnt(0)" ::: "memory");
    }
    __builtin_amdgcn_s_barrier();
    __builtin_amdgcn_sched_barrier(0);
    bf16x8 af[4], bfr[4];
    #pragma unroll
    for (int m = 0; m < 4; ++m) af[m]  = *(const bf16x8*)(&As[cur][wr*64 + m*16 + lr][lg*8]);
    #pragma unroll
    for (int n = 0; n < 4; ++n) bfr[n] = *(const bf16x8*)(&Bs[cur][wc*64 + n*16 + lr][lg*8]);
    #pragma unroll
    for (int m = 0; m < 4; ++m)
      #pragma unroll
      for (int n = 0; n < 4; ++n)
        acc[m][n] = __builtin_amdgcn_mfma_f32_16x16x32_bf16(af[m], bfr[n], acc[m][n], 0, 0, 0);
    asm volatile("s_waitcnt lgkmcnt(0)" ::: "memory");
    __builtin_amdgcn_sched_barrier(0);
    __builtin_amdgcn_s_barrier();
    __builtin_amdgcn_sched_barrier(0);
  }
#undef STAGE_

  const int seg = (EP == 5) ? (bcol / 768) : 0;     // block-uniform
  unsigned short* qkvp = nullptr;
  if (EP == 5)
    qkvp = (seg == 0) ? (unsigned short*)outv
         : (seg == 1) ? (unsigned short*)residv : (unsigned short*)aux;

  if (EP == 5 && seg == 2) {
    // v^T scatter store (per batch): vt[(b*768 + colLv)*1024 + token]
    #pragma unroll
    for (int n = 0; n < 4; ++n) {
      const int col = bcol + wc*64 + n*16 + lr;
      const float bv = bias[col];
      const int colLv = col - 1536;
      #pragma unroll
      for (int m = 0; m < 4; ++m) {
        const int row0 = brow + wr*64 + m*16 + lg*4;
        #pragma unroll
        for (int r2 = 0; r2 < 4; ++r2) {
          const int gr = row0 + r2;
          qkvp[(((size_t)(gr >> 10) * D_MODEL + colLv) << 10) + (gr & 1023)] =
              f2bf(acc[m][n][r2] + bv);
        }
      }
    }
  } else {
    // coalesced bounce: per-wave f32 tile [64 col][20 row] in SMEM (free now)
    float* Ep = (float*)SMEM + wid * 1280;
    #pragma unroll
    for (int p = 0; p < 4; ++p) {
      #pragma unroll
      for (int n = 0; n < 4; ++n) {
        const int col = bcol + wc*64 + n*16 + lr;
        const float bv = bias[col];
        f32x4 st;
        #pragma unroll
        for (int r2 = 0; r2 < 4; ++r2) {
          float v = acc[p][n][r2] + bv;
          if (EP == 1 || EP == 3) v = gelu_f(v);
          st[r2] = v;
        }
        *(f32x4*)(Ep + (n*16 + lr) * 20 + lg*4) = st;
      }
      #pragma unroll
      for (int i2 = 0; i2 < 2; ++i2) {
        const int rowL = i2*8 + (lane >> 3);
        const int colL = (lane & 7) * 8;
        const int grow = brow + wr*64 + p*16 + rowL;
        const int gcol = bcol + wc*64 + colL;
        float v[8];
        #pragma unroll
        for (int j = 0; j < 8; ++j) v[j] = Ep[(colL + j) * 20 + rowL];
        const size_t o = (size_t)grow * N + gcol;
        if (EP == 3) {
          const bf16x8 rv = *(const bf16x8*)((const __bf16*)residv + o);
          float* op = (float*)outv + o;
          float4 o0, o1;
          o0.x = v[0] + (float)rv[0]; o0.y = v[1] + (float)rv[1];
          o0.z = v[2] + (float)rv[2]; o0.w = v[3] + (float)rv[3];
          o1.x = v[4] + (float)rv[4]; o1.y = v[5] + (float)rv[5];
          o1.z = v[6] + (float)rv[6]; o1.w = v[7] + (float)rv[7];
          *(float4*)op = o0; *(float4*)(op + 4) = o1;
        } else if (EP == 2) {
          const float* rp = (const float*)residv + o;
          const float4 r0 = *(const float4*)rp, r1 = *(const float4*)(rp + 4);
          bf16x8 ov;
          ov[0] = (__bf16)(v[0] + r0.x); ov[1] = (__bf16)(v[1] + r0.y);
          ov[2] = (__bf16)(v[2] + r0.z); ov[3] = (__bf16)(v[3] + r0.w);
          ov[4] = (__bf16)(v[4] + r1.x); ov[5] = (__bf16)(v[5] + r1.y);
          ov[6] = (__bf16)(v[6] + r1.z); ov[7] = (__bf16)(v[7] + r1.w);
          *(bf16x8*)((__bf16*)outv + o) = ov;
        } else if (EP == 5) {          // q/k segment, 768-wide dest
          bf16x8 ov;
          #pragma unroll
          for (int j = 0; j < 8; ++j) ov[j] = (__bf16)v[j];
          *(bf16x8*)((__bf16*)qkvp + (size_t)grow * 768 + (gcol - seg * 768)) = ov;
        } else {                       // EP 0 / 1
          bf16x8 ov;
          #pragma unroll
          for (int j = 0; j < 8; ++j) ov[j] = (__bf16)v[j];
          *(bf16x8*)((__bf16*)outv + o) = ov;
        }
      }
    }
  }
}

// ---------------- flash attention: 768 blocks, XCD-sequential bh -----------
__global__ __launch_bounds__(512) void attn_k(
    const unsigned short* qu, const unsigned short* __restrict__ ku,
    const unsigned short* __restrict__ vtu, unsigned short* attn) {
  __shared__ __align__(16) __bf16 Kl[64][72];
  __shared__ __align__(16) __bf16 Vl[64][72];
  __shared__ __align__(16) __bf16 Pl[8][16][72];
  const __bf16* qg  = (const __bf16*)qu;
  const __bf16* kg  = (const __bf16*)ku;
  const __bf16* vtg = (const __bf16*)vtu;
  const int bid = blockIdx.x;
  const int xcd = bid & 7, idx = bid >> 3;
  const int bh = xcd * 24 + (idx >> 2);
  const int b = bh / 12, h = bh % 12;
  const int q0 = (idx & 3) * 256;
  const int tid = threadIdx.x, lane = tid & 63, w = tid >> 6;
  const int lr = lane & 15, lg = lane >> 4;
  const float scale = 0.03608439182435161f; // 1/sqrt(768)

  bf16x8 qa[2][2];
  #pragma unroll
  for (int g = 0; g < 2; ++g) {
    const int qrow = b * T_SEQ + q0 + w * 32 + g * 16 + lr;
    const __bf16* qp = qg + (size_t)qrow * D_MODEL + h * 64 + lg * 8;
    qa[g][0] = *(const bf16x8*)(qp);
    qa[g][1] = *(const bf16x8*)(qp + 32);
  }

  const __bf16* kb = kg  + (size_t)b * T_SEQ * D_MODEL + h * 64;
  const __bf16* vb = vtg + ((size_t)b * D_MODEL + h * 64) * T_SEQ;

  f32x4 o[2][4];
  float m_run[2] = {-1e30f, -1e30f}, l_run[2] = {0.f, 0.f};
  #pragma unroll
  for (int g = 0; g < 2; ++g)
    #pragma unroll
    for (int m = 0; m < 4; ++m) o[g][m] = (f32x4){0.f, 0.f, 0.f, 0.f};

  for (int kv0 = 0; kv0 < T_SEQ; kv0 += 64) {
    __syncthreads();
    {
      const int r = tid >> 3, c = (tid & 7) << 3;
      *(bf16x8*)(&Kl[r][c]) = *(const bf16x8*)(kb + (size_t)(kv0 + r) * D_MODEL + c);
      *(bf16x8*)(&Vl[r][c]) = *(const bf16x8*)(vb + (size_t)r * T_SEQ + kv0 + c);
    }
    __syncthreads();

    #pragma unroll
    for (int g = 0; g < 2; ++g) {
      f32x4 s[4];
      __builtin_amdgcn_s_setprio(1);
      #pragma unroll
      for (int m = 0; m < 4; ++m) {
        s[m] = (f32x4){0.f, 0.f, 0.f, 0.f};
        const bf16x8 kf0 = *(const bf16x8*)(&Kl[m*16 + lr][lg*8]);
        const bf16x8 kf1 = *(const bf16x8*)(&Kl[m*16 + lr][32 + lg*8]);
        s[m] = __builtin_amdgcn_mfma_f32_16x16x32_bf16(kf0, qa[g][0], s[m], 0, 0, 0);
        s[m] = __builtin_amdgcn_mfma_f32_16x16x32_bf16(kf1, qa[g][1], s[m], 0, 0, 0);
      }
      __builtin_amdgcn_s_setprio(0);
      float sv[4][4], tm = -1e30f;
      #pragma unroll
      for (int m = 0; m < 4; ++m)
        #pragma unroll
        for (int r = 0; r < 4; ++r) {
          sv[m][r] = s[m][r] * scale;
          tm = fmaxf(tm, sv[m][r]);
        }
      tm = fmaxf(tm, __shfl_xor(tm, 16));
      tm = fmaxf(tm, __shfl_xor(tm, 32));
      const float mn = fmaxf(m_run[g], tm);
      const float sc = __expf(m_run[g] - mn);
      float ts = 0.f;
      bf16x4 pk[4];
      #pragma unroll
      for (int m = 0; m < 4; ++m)
        #pragma unroll
        for (int r = 0; r < 4; ++r) {
          const float pp = __expf(sv[m][r] - mn);
          ts += pp;
          pk[m][r] = (__bf16)pp;
        }
      ts += __shfl_xor(ts, 16);
      ts += __shfl_xor(ts, 32);
      l_run[g] = l_run[g] * sc + ts;
      m_run[g] = mn;
      #pragma unroll
      for (int m = 0; m < 4; ++m)
        #pragma unroll
        for (int r = 0; r < 4; ++r) o[g][m][r] *= sc;
      #pragma unroll
      for (int m = 0; m < 4; ++m)
        *(bf16x4*)(&Pl[w][lr][16*m + 4*lg]) = pk[m];
      const bf16x8 pf0 = *(const bf16x8*)(&Pl[w][lr][lg*8]);
      const bf16x8 pf1 = *(const bf16x8*)(&Pl[w][lr][32 + lg*8]);
      __builtin_amdgcn_s_setprio(1);
      #pragma unroll
      for (int m = 0; m < 4; ++m) {
        const bf16x8 vf0 = *(const bf16x8*)(&Vl[m*16 + lr][lg*8]);
        const bf16x8 vf1 = *(const bf16x8*)(&Vl[m*16 + lr][32 + lg*8]);
        o[g][m] = __builtin_amdgcn_mfma_f32_16x16x32_bf16(vf0, pf0, o[g][m], 0, 0, 0);
        o[g][m] = __builtin_amdgcn_mfma_f32_16x16x32_bf16(vf1, pf1, o[g][m], 0, 0, 0);
      }
      __builtin_amdgcn_s_setprio(0);
    }
  }

  #pragma unroll
  for (int g = 0; g < 2; ++g) {
    const float inv = 1.0f / l_run[g];
    const int qrow = b * T_SEQ + q0 + w * 32 + g * 16 + lr;
    unsigned short* op = attn + (size_t)qrow * D_MODEL + h * 64;
    #pragma unroll
    for (int m = 0; m < 4; ++m) {
      bf16x4 ov;
      #pragma unroll
      for (int r = 0; r < 4; ++r) ov[r] = (__bf16)(o[g][m][r] * inv);
      *(bf16x4*)(op + 16*m + 4*lg) = ov;
    }
  }
}

// ---------------------------------------------------------------------------
extern "C" void kernel_launch(void* const* d_in, const int* in_sizes, int n_in,
                              void* d_out, int out_size, void* d_ws, size_t ws_size,
                              hipStream_t stream) {
  const float* x   = (const float*)d_in[0];
  const float* Wq  = (const float*)d_in[1];
  const float* bq  = (const float*)d_in[2];
  const float* Wk  = (const float*)d_in[3];
  const float* bk  = (const float*)d_in[4];
  const float* Wv  = (const float*)d_in[5];
  const float* bv  = (const float*)d_in[6];
  const float* Wo  = (const float*)d_in[7];
  const float* bo  = (const float*)d_in[8];
  const float* g1  = (const float*)d_in[9];
  const float* bt1 = (const float*)d_in[10];
  const float* g2  = (const float*)d_in[11];
  const float* bt2 = (const float*)d_in[12];
  const float* W1  = (const float*)d_in[13];
  const float* bb1 = (const float*)d_in[14];
  const float* W2  = (const float*)d_in[15];
  const float* bb2 = (const float*)d_in[16];

  const size_t SZ = (size_t)M_ROWS * D_MODEL * 2;   // 25,165,824
  char* wp = (char*)d_ws;
  unsigned short* wqkvT = (unsigned short*)wp; wp += (size_t)2304 * 768 * 2;
  unsigned short* woT   = (unsigned short*)wp; wp += (size_t)768 * 768 * 2;
  unsigned short* w1T   = (unsigned short*)wp; wp += (size_t)768 * 3072 * 2;
  unsigned short* w2T   = (unsigned short*)wp; wp += (size_t)768 * 3072 * 2;
  float*          bqkv  = (float*)wp;          wp += ((size_t)2304 * 4 + 255) & ~(size_t)255;
  unsigned short* kbuf  = (unsigned short*)wp; wp += SZ;   // k -> res2
  unsigned short* vtb   = (unsigned short*)wp;             // vT -> hid
  unsigned short* res2  = kbuf;
  unsigned short* hid   = vtb;
  const size_t avail = ws_size - (size_t)(wp - (char*)d_ws);
  const int nch = (avail >= (size_t)M_ROWS * MLP_DIM * 2) ? 1
                : (avail >= (size_t)(M_ROWS / 2) * MLP_DIM * 2) ? 2 : 4;

  unsigned short* qd = (unsigned short*)d_out;             // bf16 lo half
  unsigned short* h1 = qd + (size_t)M_ROWS * D_MODEL;      // bf16 hi half
  unsigned short* h2 = h1;

  const dim3 tb(32, 8, 1);
  wtr_k<<<dim3(24, 24), tb, 0, stream>>>(Wq, wqkvT, 768, 768);
  wtr_k<<<dim3(24, 24), tb, 0, stream>>>(Wk, wqkvT + (size_t)768 * 768, 768, 768);
  wtr_k<<<dim3(24, 24), tb, 0, stream>>>(Wv, wqkvT + (size_t)1536 * 768, 768, 768);
  wtr_k<<<dim3(24, 24), tb, 0, stream>>>(Wo, woT, 768, 768);
  wtr_k<<<dim3(96, 24), tb, 0, stream>>>(W1, w1T, 768, 3072);
  wtr_k<<<dim3(24, 96), tb, 0, stream>>>(W2, w2T, 3072, 768);
  bcat_k<<<3, 256, 0, stream>>>(bq, bk, bv, bqkv);

  ln_k<1><<<M_ROWS, 256, 0, stream>>>(x, g1, bt1, h1);

  gemm_k<5><<<dim3(128, 18), 256, 0, stream>>>(h1, wqkvT, bqkv, qd, kbuf, vtb,
                                               M_ROWS, 2304, 768, 0, 9);

  attn_k<<<dim3(768), 512, 0, stream>>>(qd, kbuf, vtb, qd);

  gemm_k<2><<<dim3(128, 6), 256, 0, stream>>>(qd, woT, bo, res2, x, nullptr,
                                              M_ROWS, 768, 768, 0, 6);

  ln_k<0><<<M_ROWS, 256, 0, stream>>>(res2, g2, bt2, h2);

  const int CH = M_ROWS / nch;
  for (int c = 0; c < nch; ++c) {
    const size_t ro = (size_t)c * CH;
    // MLP1: one dispatch, cols sequenced in groups of 12 (B-group 2.36 MB)
    gemm_k<1><<<dim3(CH / 128, 24), 256, 0, stream>>>(h2 + ro * 768, w1T, bb1,
        hid, nullptr, nullptr, CH, 3072, 768, 0, 12);
    gemm_k<3><<<dim3(CH / 128, 6), 256, 0, stream>>>(hid, w2T, bb2,
        (float*)d_out + ro * 768, res2 + ro * 768, nullptr, CH, 768, 3072, 0, 6);
  }
}

// Round 12
// 508.281 us; speedup vs baseline: 4.7970x; 1.0284x over previous
//
#include <hip/hip_runtime.h>
#include <hip/hip_bf16.h>
#include <math.h>

#define D_MODEL 768
#define T_SEQ   1024
#define B_BATCH 16
#define MLP_DIM 3072
#define M_ROWS  (B_BATCH * T_SEQ)   // 16384

typedef __attribute__((ext_vector_type(8))) __bf16          bf16x8;
typedef __attribute__((ext_vector_type(4))) __bf16          bf16x4;
typedef __attribute__((ext_vector_type(4))) float           f32x4;

__device__ __forceinline__ float bf2f(unsigned short u) {
  union { unsigned int u; float f; } w; w.u = ((unsigned int)u) << 16; return w.f;
}
__device__ __forceinline__ unsigned short f2bf(float f) {
  union { float f; unsigned int u; } w; w.f = f;
  unsigned int r = (w.u + 0x7fffu + ((w.u >> 16) & 1u)) >> 16;
  return (unsigned short)r;
}
__device__ __forceinline__ float gelu_f(float x) {
  return 0.5f * x * (1.0f + erff(x * 0.70710678118654752f));
}
// async global->LDS, 16B per lane; LDS dest = wave-uniform base + lane*16
__device__ __forceinline__ void gload16(const void* g, void* l) {
  __builtin_amdgcn_global_load_lds(
      (const __attribute__((address_space(1))) unsigned int*)g,
      (__attribute__((address_space(3))) unsigned int*)l, 16, 0, 0);
}

// ------- weight transpose+convert: dst[N=C][K=R] bf16 = src[R][C] f32 ------
__global__ void wtr_k(const float* __restrict__ src,
                      unsigned short* __restrict__ dst, int R, int C) {
  __shared__ float t[32][33];
  const int c0 = blockIdx.x * 32, r0 = blockIdx.y * 32;
  const int tx = threadIdx.x, ty = threadIdx.y;
  #pragma unroll
  for (int j = 0; j < 32; j += 8)
    t[ty + j][tx] = src[(size_t)(r0 + ty + j) * C + (c0 + tx)];
  __syncthreads();
  #pragma unroll
  for (int j = 0; j < 32; j += 8)
    dst[(size_t)(c0 + ty + j) * R + (r0 + tx)] = f2bf(t[tx][ty + j]);
}

// ------- concat 3 bias vectors of 768 f32 --------------------------------
__global__ void bcat_k(const float* __restrict__ a, const float* __restrict__ b,
                       const float* __restrict__ c, float* __restrict__ o) {
  const int i = blockIdx.x * 256 + threadIdx.x;
  if (i < 768) { o[i] = a[i]; o[i + 768] = b[i]; o[i + 1536] = c[i]; }
}

// ---------- fused LayerNorm (stats + apply), one block per row -------------
template<int SRC_F32>
__global__ __launch_bounds__(256) void ln_k(const void* __restrict__ src,
    const float* __restrict__ g, const float* __restrict__ b,
    unsigned short* __restrict__ out) {
  const int row = blockIdx.x, tid = threadIdx.x;
  const size_t base = (size_t)row * D_MODEL;
  float v[3];
  #pragma unroll
  for (int i = 0; i < 3; ++i) {
    const int c = tid + (i << 8);
    v[i] = SRC_F32 ? ((const float*)src)[base + c]
                   : bf2f(((const unsigned short*)src)[base + c]);
  }
  float s  = v[0] + v[1] + v[2];
  float sq = v[0]*v[0] + v[1]*v[1] + v[2]*v[2];
  #pragma unroll
  for (int m = 32; m; m >>= 1) { s += __shfl_xor(s, m); sq += __shfl_xor(sq, m); }
  __shared__ float ps[4], pq[4];
  if ((tid & 63) == 0) { ps[tid >> 6] = s; pq[tid >> 6] = sq; }
  __syncthreads();
  s  = ps[0] + ps[1] + ps[2] + ps[3];
  sq = pq[0] + pq[1] + pq[2] + pq[3];
  const float mu  = s * (1.0f / 768.0f);
  const float var = sq * (1.0f / 768.0f) - mu * mu;
  const float inv = rsqrtf(var + 1e-5f);
  #pragma unroll
  for (int i = 0; i < 3; ++i) {
    const int c = tid + (i << 8);
    out[base + c] = f2bf((v[i] - mu) * inv * g[c] + b[c]);
  }
}

// ---- GEMM: C[M,N] = A[M,K](bf16) @ Bt[N,K]^T(bf16) + bias(f32) ------------
// 256x256 tile, BK=64, 8 waves (2x4), dbuf 128KB LDS, st_16x32 swizzle.
// Swizzle (both-sides, #21): LDS linear gload dest + inverse-swizzled global
// source; ds_read applies  cc = (c&31) ^ (((r>>3)&1)<<4)  within 16x32
// subtiles:  addr_el(r,c) = ((r>>4)*2 + (c>>5))*512 + (r&15)*32 + cc.
// Block map: XCD row-stripe + col groups of cgrp (B-group L2-resident).
// EP 0: bf16 | 1: gelu->bf16 | 2: +resid(f32)->bf16 | 3: gelu+resid(bf16)->f32
// EP 5: fused QKV split store (outv=q, residv=k, aux=v^T layout)
template<int EP>
__global__ __launch_bounds__(512) void gemm_k(
    const unsigned short* __restrict__ Au, const unsigned short* __restrict__ Btu,
    const float* __restrict__ bias, void* __restrict__ outv,
    const void* __restrict__ residv, void* __restrict__ aux,
    int M, int N, int K, int cgrp) {
  __shared__ __align__(16) __bf16 SMEM[2 * 32768];          // 128 KB
  const __bf16* A  = (const __bf16*)Au;
  const __bf16* Bt = (const __bf16*)Btu;
  const int tid = threadIdx.x;
  const int lane = tid & 63, w = tid >> 6;      // 8 waves
  const int wr = w >> 2, wc = w & 3;            // 2 x 4 wave grid
  const int lr = lane & 15, lg = lane >> 4;
  // XCD row-stripe + col-group mapping (gx % 8 == 0, gy % cgrp == 0)
  const int gx = gridDim.x, gy = gridDim.y;
  const int bid = blockIdx.y * gx + blockIdx.x;
  const int xcd = bid & 7, idx = bid >> 3;
  const int rpx = gx >> 3;
  const int gsz = rpx * cgrp;
  const int grp = idx / gsz, rem = idx - grp * gsz;
  const int rb = rem / cgrp, cc2 = rem - rb * cgrp + grp * cgrp;
  const int brow = (xcd * rpx + rb) * 256;
  const int bcol = cc2 * 256;

  f32x4 acc[8][4];
  #pragma unroll
  for (int m = 0; m < 8; ++m)
    #pragma unroll
    for (int n = 0; n < 4; ++n) acc[m][n] = (f32x4){0.f, 0.f, 0.f, 0.f};

  // ---- staging precompute: wave w + gload g covers subtile s = g*8+w ----
  const int rrs = lane >> 2;                 // 0..15 within subtile
  const int ccs = (lane & 3) << 3;           // 0,8,16,24
  const int csw = ccs ^ ((rrs >> 3) << 4);   // inverse swizzle on source
  const __bf16* sA[4]; const __bf16* sB[4]; int dA[4], dB[4];
  #pragma unroll
  for (int g = 0; g < 4; ++g) {
    const int s = g * 8 + w;
    const int rsrc = (s >> 1) * 16 + rrs;
    const int csrc = (s & 1) * 32 + csw;
    sA[g] = A  + (size_t)(brow + rsrc) * K + csrc;
    sB[g] = Bt + (size_t)(bcol + rsrc) * K + csrc;
    dA[g] = s * 512;
    dB[g] = 16384 + s * 512;
  }

#define STAGE_(buf_, k0_) do {                                     \
    _Pragma("unroll")                                              \
    for (int g = 0; g < 4; ++g) {                                  \
      gload16(sA[g] + (k0_), &SMEM[(buf_) * 32768 + dA[g]]);       \
      gload16(sB[g] + (k0_), &SMEM[(buf_) * 32768 + dB[g]]);       \
    }                                                              \
  } while (0)

  // ---- read-side swizzled offsets ----
  const int rbase = lr * 32 + ((lg << 3) ^ (((lr >> 3) & 1) << 4));

  STAGE_(0, 0);
  int cur = 0;
  for (int k0 = 0; k0 < K; k0 += 64, cur ^= 1) {
    if (k0 + 64 < K) {
      STAGE_(cur ^ 1, k0 + 64);
      asm volatile("s_waitcnt vmcnt(8)" ::: "memory");
    } else {
      asm volatile("s_waitcnt vmcnt(0)" ::: "memory");
    }
    __builtin_amdgcn_s_barrier();
    __builtin_amdgcn_sched_barrier(0);
    const int bb = cur * 32768;
    bf16x8 bfr[4][2];
    #pragma unroll
    for (int n = 0; n < 4; ++n)
      #pragma unroll
      for (int kk = 0; kk < 2; ++kk)
        bfr[n][kk] = *(const bf16x8*)(&SMEM[bb + 16384 + ((wc*4 + n)*2 + kk)*512 + rbase]);
    __builtin_amdgcn_s_setprio(1);
    #pragma unroll
    for (int mq = 0; mq < 2; ++mq) {
      bf16x8 af[4][2];
      #pragma unroll
      for (int ml = 0; ml < 4; ++ml)
        #pragma unroll
        for (int kk = 0; kk < 2; ++kk)
          af[ml][kk] = *(const bf16x8*)(&SMEM[bb + ((wr*8 + mq*4 + ml)*2 + kk)*512 + rbase]);
      #pragma unroll
      for (int ml = 0; ml < 4; ++ml)
        #pragma unroll
        for (int n = 0; n < 4; ++n) {
          acc[mq*4+ml][n] = __builtin_amdgcn_mfma_f32_16x16x32_bf16(af[ml][0], bfr[n][0], acc[mq*4+ml][n], 0, 0, 0);
          acc[mq*4+ml][n] = __builtin_amdgcn_mfma_f32_16x16x32_bf16(af[ml][1], bfr[n][1], acc[mq*4+ml][n], 0, 0, 0);
        }
    }
    __builtin_amdgcn_s_setprio(0);
    asm volatile("s_waitcnt lgkmcnt(0)" ::: "memory");
    __builtin_amdgcn_sched_barrier(0);
    __builtin_amdgcn_s_barrier();
    __builtin_amdgcn_sched_barrier(0);
  }
#undef STAGE_

  const int seg = (EP == 5) ? (bcol / 768) : 0;     // block-uniform (256|768 grid)
  unsigned short* qkvp = nullptr;
  if (EP == 5)
    qkvp = (seg == 0) ? (unsigned short*)outv
         : (seg == 1) ? (unsigned short*)residv : (unsigned short*)aux;

  if (EP == 5 && seg == 2) {
    // v^T scatter store (per batch): vt[(b*768 + colLv)*1024 + token]
    #pragma unroll
    for (int n = 0; n < 4; ++n) {
      const int col = bcol + wc*64 + n*16 + lr;
      const float bv = bias[col];
      const int colLv = col - 1536;
      #pragma unroll
      for (int m = 0; m < 8; ++m) {
        const int row0 = brow + wr*128 + m*16 + lg*4;
        #pragma unroll
        for (int r2 = 0; r2 < 4; ++r2) {
          const int gr = row0 + r2;
          qkvp[(((size_t)(gr >> 10) * D_MODEL + colLv) << 10) + (gr & 1023)] =
              f2bf(acc[m][n][r2] + bv);
        }
      }
    }
  } else {
    // coalesced bounce: per-wave f32 tile [64 col][20 row] in SMEM (free now)
    float* Ep = (float*)SMEM + w * 1280;   // 5120 B per wave
    #pragma unroll
    for (int m = 0; m < 8; ++m) {
      #pragma unroll
      for (int n = 0; n < 4; ++n) {
        const int col = bcol + wc*64 + n*16 + lr;
        const float bv = bias[col];
        f32x4 st;
        #pragma unroll
        for (int r2 = 0; r2 < 4; ++r2) {
          float v = acc[m][n][r2] + bv;
          if (EP == 1 || EP == 3) v = gelu_f(v);
          st[r2] = v;
        }
        *(f32x4*)(Ep + (n*16 + lr) * 20 + lg*4) = st;
      }
      #pragma unroll
      for (int i2 = 0; i2 < 2; ++i2) {
        const int rowL = i2*8 + (lane >> 3);
        const int colL = (lane & 7) * 8;
        const int grow = brow + wr*128 + m*16 + rowL;
        const int gcol = bcol + wc*64 + colL;
        float v[8];
        #pragma unroll
        for (int j = 0; j < 8; ++j) v[j] = Ep[(colL + j) * 20 + rowL];
        const size_t o = (size_t)grow * N + gcol;
        if (EP == 3) {
          const bf16x8 rv = *(const bf16x8*)((const __bf16*)residv + o);
          float* op = (float*)outv + o;
          float4 o0, o1;
          o0.x = v[0] + (float)rv[0]; o0.y = v[1] + (float)rv[1];
          o0.z = v[2] + (float)rv[2]; o0.w = v[3] + (float)rv[3];
          o1.x = v[4] + (float)rv[4]; o1.y = v[5] + (float)rv[5];
          o1.z = v[6] + (float)rv[6]; o1.w = v[7] + (float)rv[7];
          *(float4*)op = o0; *(float4*)(op + 4) = o1;
        } else if (EP == 2) {
          const float* rp = (const float*)residv + o;
          const float4 r0 = *(const float4*)rp, r1 = *(const float4*)(rp + 4);
          bf16x8 ov;
          ov[0] = (__bf16)(v[0] + r0.x); ov[1] = (__bf16)(v[1] + r0.y);
          ov[2] = (__bf16)(v[2] + r0.z); ov[3] = (__bf16)(v[3] + r0.w);
          ov[4] = (__bf16)(v[4] + r1.x); ov[5] = (__bf16)(v[5] + r1.y);
          ov[6] = (__bf16)(v[6] + r1.z); ov[7] = (__bf16)(v[7] + r1.w);
          *(bf16x8*)((__bf16*)outv + o) = ov;
        } else if (EP == 5) {          // q/k segment, 768-wide dest
          bf16x8 ov;
          #pragma unroll
          for (int j = 0; j < 8; ++j) ov[j] = (__bf16)v[j];
          *(bf16x8*)((__bf16*)qkvp + (size_t)grow * 768 + (gcol - seg * 768)) = ov;
        } else {                       // EP 0 / 1
          bf16x8 ov;
          #pragma unroll
          for (int j = 0; j < 8; ++j) ov[j] = (__bf16)v[j];
          *(bf16x8*)((__bf16*)outv + o) = ov;
        }
      }
    }
  }
}

// ---------------- flash attention: 768 blocks, XCD-sequential bh -----------
__global__ __launch_bounds__(512) void attn_k(
    const unsigned short* qu, const unsigned short* __restrict__ ku,
    const unsigned short* __restrict__ vtu, unsigned short* attn) {
  __shared__ __align__(16) __bf16 Kl[64][72];
  __shared__ __align__(16) __bf16 Vl[64][72];
  __shared__ __align__(16) __bf16 Pl[8][16][72];
  const __bf16* qg  = (const __bf16*)qu;
  const __bf16* kg  = (const __bf16*)ku;
  const __bf16* vtg = (const __bf16*)vtu;
  const int bid = blockIdx.x;
  const int xcd = bid & 7, idx = bid >> 3;
  const int bh = xcd * 24 + (idx >> 2);
  const int b = bh / 12, h = bh % 12;
  const int q0 = (idx & 3) * 256;
  const int tid = threadIdx.x, lane = tid & 63, w = tid >> 6;
  const int lr = lane & 15, lg = lane >> 4;
  const float scale = 0.03608439182435161f; // 1/sqrt(768)

  bf16x8 qa[2][2];
  #pragma unroll
  for (int g = 0; g < 2; ++g) {
    const int qrow = b * T_SEQ + q0 + w * 32 + g * 16 + lr;
    const __bf16* qp = qg + (size_t)qrow * D_MODEL + h * 64 + lg * 8;
    qa[g][0] = *(const bf16x8*)(qp);
    qa[g][1] = *(const bf16x8*)(qp + 32);
  }

  const __bf16* kb = kg  + (size_t)b * T_SEQ * D_MODEL + h * 64;
  const __bf16* vb = vtg + ((size_t)b * D_MODEL + h * 64) * T_SEQ;

  f32x4 o[2][4];
  float m_run[2] = {-1e30f, -1e30f}, l_run[2] = {0.f, 0.f};
  #pragma unroll
  for (int g = 0; g < 2; ++g)
    #pragma unroll
    for (int m = 0; m < 4; ++m) o[g][m] = (f32x4){0.f, 0.f, 0.f, 0.f};

  for (int kv0 = 0; kv0 < T_SEQ; kv0 += 64) {
    __syncthreads();
    {
      const int r = tid >> 3, c = (tid & 7) << 3;
      *(bf16x8*)(&Kl[r][c]) = *(const bf16x8*)(kb + (size_t)(kv0 + r) * D_MODEL + c);
      *(bf16x8*)(&Vl[r][c]) = *(const bf16x8*)(vb + (size_t)r * T_SEQ + kv0 + c);
    }
    __syncthreads();

    #pragma unroll
    for (int g = 0; g < 2; ++g) {
      f32x4 s[4];
      __builtin_amdgcn_s_setprio(1);
      #pragma unroll
      for (int m = 0; m < 4; ++m) {
        s[m] = (f32x4){0.f, 0.f, 0.f, 0.f};
        const bf16x8 kf0 = *(const bf16x8*)(&Kl[m*16 + lr][lg*8]);
        const bf16x8 kf1 = *(const bf16x8*)(&Kl[m*16 + lr][32 + lg*8]);
        s[m] = __builtin_amdgcn_mfma_f32_16x16x32_bf16(kf0, qa[g][0], s[m], 0, 0, 0);
        s[m] = __builtin_amdgcn_mfma_f32_16x16x32_bf16(kf1, qa[g][1], s[m], 0, 0, 0);
      }
      __builtin_amdgcn_s_setprio(0);
      float sv[4][4], tm = -1e30f;
      #pragma unroll
      for (int m = 0; m < 4; ++m)
        #pragma unroll
        for (int r = 0; r < 4; ++r) {
          sv[m][r] = s[m][r] * scale;
          tm = fmaxf(tm, sv[m][r]);
        }
      tm = fmaxf(tm, __shfl_xor(tm, 16));
      tm = fmaxf(tm, __shfl_xor(tm, 32));
      const float mn = fmaxf(m_run[g], tm);
      const float sc = __expf(m_run[g] - mn);
      float ts = 0.f;
      bf16x4 pk[4];
      #pragma unroll
      for (int m = 0; m < 4; ++m)
        #pragma unroll
        for (int r = 0; r < 4; ++r) {
          const float pp = __expf(sv[m][r] - mn);
          ts += pp;
          pk[m][r] = (__bf16)pp;
        }
      ts += __shfl_xor(ts, 16);
      ts += __shfl_xor(ts, 32);
      l_run[g] = l_run[g] * sc + ts;
      m_run[g] = mn;
      #pragma unroll
      for (int m = 0; m < 4; ++m)
        #pragma unroll
        for (int r = 0; r < 4; ++r) o[g][m][r] *= sc;
      #pragma unroll
      for (int m = 0; m < 4; ++m)
        *(bf16x4*)(&Pl[w][lr][16*m + 4*lg]) = pk[m];
      const bf16x8 pf0 = *(const bf16x8*)(&Pl[w][lr][lg*8]);
      const bf16x8 pf1 = *(const bf16x8*)(&Pl[w][lr][32 + lg*8]);
      __builtin_amdgcn_s_setprio(1);
      #pragma unroll
      for (int m = 0; m < 4; ++m) {
        const bf16x8 vf0 = *(const bf16x8*)(&Vl[m*16 + lr][lg*8]);
        const bf16x8 vf1 = *(const bf16x8*)(&Vl[m*16 + lr][32 + lg*8]);
        o[g][m] = __builtin_amdgcn_mfma_f32_16x16x32_bf16(vf0, pf0, o[g][m], 0, 0, 0);
        o[g][m] = __builtin_amdgcn_mfma_f32_16x16x32_bf16(vf1, pf1, o[g][m], 0, 0, 0);
      }
      __builtin_amdgcn_s_setprio(0);
    }
  }

  #pragma unroll
  for (int g = 0; g < 2; ++g) {
    const float inv = 1.0f / l_run[g];
    const int qrow = b * T_SEQ + q0 + w * 32 + g * 16 + lr;
    unsigned short* op = attn + (size_t)qrow * D_MODEL + h * 64;
    #pragma unroll
    for (int m = 0; m < 4; ++m) {
      bf16x4 ov;
      #pragma unroll
      for (int r = 0; r < 4; ++r) ov[r] = (__bf16)(o[g][m][r] * inv);
      *(bf16x4*)(op + 16*m + 4*lg) = ov;
    }
  }
}

// ---------------------------------------------------------------------------
extern "C" void kernel_launch(void* const* d_in, const int* in_sizes, int n_in,
                              void* d_out, int out_size, void* d_ws, size_t ws_size,
                              hipStream_t stream) {
  const float* x   = (const float*)d_in[0];
  const float* Wq  = (const float*)d_in[1];
  const float* bq  = (const float*)d_in[2];
  const float* Wk  = (const float*)d_in[3];
  const float* bk  = (const float*)d_in[4];
  const float* Wv  = (const float*)d_in[5];
  const float* bv  = (const float*)d_in[6];
  const float* Wo  = (const float*)d_in[7];
  const float* bo  = (const float*)d_in[8];
  const float* g1  = (const float*)d_in[9];
  const float* bt1 = (const float*)d_in[10];
  const float* g2  = (const float*)d_in[11];
  const float* bt2 = (const float*)d_in[12];
  const float* W1  = (const float*)d_in[13];
  const float* bb1 = (const float*)d_in[14];
  const float* W2  = (const float*)d_in[15];
  const float* bb2 = (const float*)d_in[16];

  const size_t SZ = (size_t)M_ROWS * D_MODEL * 2;   // 25,165,824
  char* wp = (char*)d_ws;
  unsigned short* wqkvT = (unsigned short*)wp; wp += (size_t)2304 * 768 * 2;
  unsigned short* woT   = (unsigned short*)wp; wp += (size_t)768 * 768 * 2;
  unsigned short* w1T   = (unsigned short*)wp; wp += (size_t)768 * 3072 * 2;
  unsigned short* w2T   = (unsigned short*)wp; wp += (size_t)768 * 3072 * 2;
  float*          bqkv  = (float*)wp;          wp += ((size_t)2304 * 4 + 255) & ~(size_t)255;
  unsigned short* kbuf  = (unsigned short*)wp; wp += SZ;   // k -> res2
  unsigned short* vtb   = (unsigned short*)wp;             // vT -> hid
  unsigned short* res2  = kbuf;
  unsigned short* hid   = vtb;
  const size_t avail = ws_size - (size_t)(wp - (char*)d_ws);
  const int nch = (avail >= (size_t)M_ROWS * MLP_DIM * 2) ? 1
                : (avail >= (size_t)(M_ROWS / 2) * MLP_DIM * 2) ? 2 : 4;

  unsigned short* qd = (unsigned short*)d_out;             // bf16 lo half
  unsigned short* h1 = qd + (size_t)M_ROWS * D_MODEL;      // bf16 hi half
  unsigned short* h2 = h1;

  const dim3 tb(32, 8, 1);
  wtr_k<<<dim3(24, 24), tb, 0, stream>>>(Wq, wqkvT, 768, 768);
  wtr_k<<<dim3(24, 24), tb, 0, stream>>>(Wk, wqkvT + (size_t)768 * 768, 768, 768);
  wtr_k<<<dim3(24, 24), tb, 0, stream>>>(Wv, wqkvT + (size_t)1536 * 768, 768, 768);
  wtr_k<<<dim3(24, 24), tb, 0, stream>>>(Wo, woT, 768, 768);
  wtr_k<<<dim3(96, 24), tb, 0, stream>>>(W1, w1T, 768, 3072);
  wtr_k<<<dim3(24, 96), tb, 0, stream>>>(W2, w2T, 3072, 768);
  bcat_k<<<3, 256, 0, stream>>>(bq, bk, bv, bqkv);

  ln_k<1><<<M_ROWS, 256, 0, stream>>>(x, g1, bt1, h1);

  gemm_k<5><<<dim3(64, 9), 512, 0, stream>>>(h1, wqkvT, bqkv, qd, kbuf, vtb,
                                             M_ROWS, 2304, 768, 9);

  attn_k<<<dim3(768), 512, 0, stream>>>(qd, kbuf, vtb, qd);

  gemm_k<2><<<dim3(64, 3), 512, 0, stream>>>(qd, woT, bo, res2, x, nullptr,
                                             M_ROWS, 768, 768, 3);

  ln_k<0><<<M_ROWS, 256, 0, stream>>>(res2, g2, bt2, h2);

  const int CH = M_ROWS / nch;
  for (int c = 0; c < nch; ++c) {
    const size_t ro = (size_t)c * CH;
    gemm_k<1><<<dim3(CH / 256, 12), 512, 0, stream>>>(h2 + ro * 768, w1T, bb1,
        hid, nullptr, nullptr, CH, 3072, 768, 6);
    gemm_k<3><<<dim3(CH / 256, 3), 512, 0, stream>>>(hid, w2T, bb2,
        (float*)d_out + ro * 768, res2 + ro * 768, nullptr, CH, 768, 3072, 3);
  }
}

// Round 13
// 499.968 us; speedup vs baseline: 4.8768x; 1.0166x over previous
//
#include <hip/hip_runtime.h>
#include <hip/hip_bf16.h>
#include <math.h>

#define D_MODEL 768
#define T_SEQ   1024
#define B_BATCH 16
#define MLP_DIM 3072
#define M_ROWS  (B_BATCH * T_SEQ)   // 16384

typedef __attribute__((ext_vector_type(8))) __bf16          bf16x8;
typedef __attribute__((ext_vector_type(4))) __bf16          bf16x4;
typedef __attribute__((ext_vector_type(4))) float           f32x4;

__device__ __forceinline__ float bf2f(unsigned short u) {
  union { unsigned int u; float f; } w; w.u = ((unsigned int)u) << 16; return w.f;
}
__device__ __forceinline__ unsigned short f2bf(float f) {
  union { float f; unsigned int u; } w; w.f = f;
  unsigned int r = (w.u + 0x7fffu + ((w.u >> 16) & 1u)) >> 16;
  return (unsigned short)r;
}
__device__ __forceinline__ float gelu_f(float x) {
  return 0.5f * x * (1.0f + erff(x * 0.70710678118654752f));
}
// async global->LDS, 16B per lane; LDS dest = wave-uniform base + lane*16
__device__ __forceinline__ void gload16(const void* g, void* l) {
  __builtin_amdgcn_global_load_lds(
      (const __attribute__((address_space(1))) unsigned int*)g,
      (__attribute__((address_space(3))) unsigned int*)l, 16, 0, 0);
}

// ------- weight transpose+convert: dst[N=C][K=R] bf16 = src[R][C] f32 ------
__global__ void wtr_k(const float* __restrict__ src,
                      unsigned short* __restrict__ dst, int R, int C) {
  __shared__ float t[32][33];
  const int c0 = blockIdx.x * 32, r0 = blockIdx.y * 32;
  const int tx = threadIdx.x, ty = threadIdx.y;
  #pragma unroll
  for (int j = 0; j < 32; j += 8)
    t[ty + j][tx] = src[(size_t)(r0 + ty + j) * C + (c0 + tx)];
  __syncthreads();
  #pragma unroll
  for (int j = 0; j < 32; j += 8)
    dst[(size_t)(c0 + ty + j) * R + (r0 + tx)] = f2bf(t[tx][ty + j]);
}

// ------- concat 3 bias vectors of 768 f32 --------------------------------
__global__ void bcat_k(const float* __restrict__ a, const float* __restrict__ b,
                       const float* __restrict__ c, float* __restrict__ o) {
  const int i = blockIdx.x * 256 + threadIdx.x;
  if (i < 768) { o[i] = a[i]; o[i + 768] = b[i]; o[i + 1536] = c[i]; }
}

// ---------- fused LayerNorm (stats + apply), one block per row -------------
template<int SRC_F32>
__global__ __launch_bounds__(256) void ln_k(const void* __restrict__ src,
    const float* __restrict__ g, const float* __restrict__ b,
    unsigned short* __restrict__ out) {
  const int row = blockIdx.x, tid = threadIdx.x;
  const size_t base = (size_t)row * D_MODEL;
  float v[3];
  #pragma unroll
  for (int i = 0; i < 3; ++i) {
    const int c = tid + (i << 8);
    v[i] = SRC_F32 ? ((const float*)src)[base + c]
                   : bf2f(((const unsigned short*)src)[base + c]);
  }
  float s  = v[0] + v[1] + v[2];
  float sq = v[0]*v[0] + v[1]*v[1] + v[2]*v[2];
  #pragma unroll
  for (int m = 32; m; m >>= 1) { s += __shfl_xor(s, m); sq += __shfl_xor(sq, m); }
  __shared__ float ps[4], pq[4];
  if ((tid & 63) == 0) { ps[tid >> 6] = s; pq[tid >> 6] = sq; }
  __syncthreads();
  s  = ps[0] + ps[1] + ps[2] + ps[3];
  sq = pq[0] + pq[1] + pq[2] + pq[3];
  const float mu  = s * (1.0f / 768.0f);
  const float var = sq * (1.0f / 768.0f) - mu * mu;
  const float inv = rsqrtf(var + 1e-5f);
  #pragma unroll
  for (int i = 0; i < 3; ++i) {
    const int c = tid + (i << 8);
    out[base + c] = f2bf((v[i] - mu) * inv * g[c] + b[c]);
  }
}

// ---- GEMM: C[M,N] = A[M,K](bf16) @ Bt[N,K]^T(bf16) + bias(f32) ------------
// 256x256 tile, BK=64, 8 waves (2x4), dbuf 128KB LDS.
// 4-phase K-step (m201-style): per phase {ds_read subtile group, stage 2
// gloads of next tile, lgkmcnt(0)+sched_barrier, setprio(1), 16 MFMA,
// setprio(0), barrier}. Counted vmcnt(2) once per tile (P1) — next-tile
// loads stay in flight across barriers.
// Swizzle (both-sides, #21): read col = lg*8 ^ ((lr>>1)&3)<<3; source
// pre-swizzled with the same involution; bank-group (lr&1, lg^((lr>>1)&3))
// -> 2 lanes/group (free).
// Block map: XCD row-stripe + col groups of cgrp (B-group L2-resident).
// EP 0: bf16 | 1: gelu->bf16 | 2: +resid(f32)->bf16 | 3: gelu+resid(bf16)->f32
// EP 5: fused QKV split store (outv=q, residv=k, aux=v^T layout)
template<int EP>
__global__ __launch_bounds__(512) void gemm_k(
    const unsigned short* __restrict__ Au, const unsigned short* __restrict__ Btu,
    const float* __restrict__ bias, void* __restrict__ outv,
    const void* __restrict__ residv, void* __restrict__ aux,
    int M, int N, int K, int cgrp) {
  __shared__ __align__(16) __bf16 SMEM[2 * 32768];          // 128 KB
  const __bf16* A  = (const __bf16*)Au;
  const __bf16* Bt = (const __bf16*)Btu;
  const int tid = threadIdx.x;
  const int lane = tid & 63, w = tid >> 6;      // 8 waves
  const int wr = w >> 2, wc = w & 3;            // 2 x 4 wave grid
  const int lr = lane & 15, lg = lane >> 4;
  // XCD row-stripe + col-group mapping (gx % 8 == 0, gy % cgrp == 0)
  const int gx = gridDim.x;
  const int bid = blockIdx.y * gx + blockIdx.x;
  const int xcd = bid & 7, idx = bid >> 3;
  const int rpx = gx >> 3;
  const int gsz = rpx * cgrp;
  const int grp = idx / gsz, rem = idx - grp * gsz;
  const int rb = rem / cgrp, cc2 = rem - rb * cgrp + grp * cgrp;
  const int brow = (xcd * rpx + rb) * 256;
  const int bcol = cc2 * 256;

  f32x4 acc[8][4];
  #pragma unroll
  for (int m = 0; m < 8; ++m)
    #pragma unroll
    for (int n = 0; n < 4; ++n) acc[m][n] = (f32x4){0.f, 0.f, 0.f, 0.f};

  // ---- staging: wave w + phase g covers subtile s = g*8+w (A and B) ----
  const int rrs = lane >> 2;                 // 0..15 within subtile
  const int ccs = (lane & 3) << 3;           // 0,8,16,24
  // inverse swizzle on global source: XOR col bits 3-4 with row bits 1-2
  const int csw = ccs ^ ((((lane >> 3) & 3)) << 3);
  const __bf16* sA[4]; const __bf16* sB[4]; int dA[4], dB[4];
  #pragma unroll
  for (int g = 0; g < 4; ++g) {
    const int s = g * 8 + w;
    const int rsrc = (s >> 1) * 16 + rrs;
    const int csrc = (s & 1) * 32 + csw;
    sA[g] = A  + (size_t)(brow + rsrc) * K + csrc;
    sB[g] = Bt + (size_t)(bcol + rsrc) * K + csrc;
    dA[g] = s * 512;
    dB[g] = 16384 + s * 512;
  }

#define STAGE2_(nbb_, k0_, g_) do {                         \
    gload16(sA[g_] + (k0_), &SMEM[(nbb_) + dA[g_]]);        \
    gload16(sB[g_] + (k0_), &SMEM[(nbb_) + dB[g_]]);        \
  } while (0)

  // read-side swizzled base (element offset within a 512-el subtile)
  const int rbase = lr * 32 + ((lg << 3) ^ (((lr >> 1) & 3) << 3));

  // prologue: full tile 0 into buf0
  #pragma unroll
  for (int g = 0; g < 4; ++g) STAGE2_(0, 0, g);

  int cur = 0;
  for (int k0 = 0; k0 < K; k0 += 64, cur ^= 1) {
    const int bb  = cur * 32768;
    const int nbb = (cur ^ 1) * 32768;
    const bool pf = (k0 + 64 < K);
    bf16x8 af0[4][2], af1[4][2], bfr[4][2];
    // ---------------- P1 ----------------
    if (pf) {
      STAGE2_(nbb, k0 + 64, 0);
      asm volatile("s_waitcnt vmcnt(2)" ::: "memory");
    } else {
      asm volatile("s_waitcnt vmcnt(0)" ::: "memory");
    }
    __builtin_amdgcn_s_barrier();
    __builtin_amdgcn_sched_barrier(0);
    #pragma unroll
    for (int ml = 0; ml < 4; ++ml)
      #pragma unroll
      for (int kk = 0; kk < 2; ++kk)
        af0[ml][kk] = *(const bf16x8*)(&SMEM[bb + ((wr*8 + ml)*2 + kk)*512 + rbase]);
    #pragma unroll
    for (int n = 0; n < 2; ++n)
      #pragma unroll
      for (int kk = 0; kk < 2; ++kk)
        bfr[n][kk] = *(const bf16x8*)(&SMEM[bb + 16384 + ((wc*4 + n)*2 + kk)*512 + rbase]);
    asm volatile("s_waitcnt lgkmcnt(0)" ::: "memory");
    __builtin_amdgcn_sched_barrier(0);
    __builtin_amdgcn_s_setprio(1);
    #pragma unroll
    for (int ml = 0; ml < 4; ++ml)
      #pragma unroll
      for (int n = 0; n < 2; ++n) {
        acc[ml][n] = __builtin_amdgcn_mfma_f32_16x16x32_bf16(af0[ml][0], bfr[n][0], acc[ml][n], 0, 0, 0);
        acc[ml][n] = __builtin_amdgcn_mfma_f32_16x16x32_bf16(af0[ml][1], bfr[n][1], acc[ml][n], 0, 0, 0);
      }
    __builtin_amdgcn_s_setprio(0);
    __builtin_amdgcn_s_barrier();
    // ---------------- P2 ----------------
    #pragma unroll
    for (int n = 2; n < 4; ++n)
      #pragma unroll
      for (int kk = 0; kk < 2; ++kk)
        bfr[n][kk] = *(const bf16x8*)(&SMEM[bb + 16384 + ((wc*4 + n)*2 + kk)*512 + rbase]);
    if (pf) STAGE2_(nbb, k0 + 64, 1);
    asm volatile("s_waitcnt lgkmcnt(0)" ::: "memory");
    __builtin_amdgcn_sched_barrier(0);
    __builtin_amdgcn_s_setprio(1);
    #pragma unroll
    for (int ml = 0; ml < 4; ++ml)
      #pragma unroll
      for (int n = 2; n < 4; ++n) {
        acc[ml][n] = __builtin_amdgcn_mfma_f32_16x16x32_bf16(af0[ml][0], bfr[n][0], acc[ml][n], 0, 0, 0);
        acc[ml][n] = __builtin_amdgcn_mfma_f32_16x16x32_bf16(af0[ml][1], bfr[n][1], acc[ml][n], 0, 0, 0);
      }
    __builtin_amdgcn_s_setprio(0);
    __builtin_amdgcn_s_barrier();
    // ---------------- P3 ----------------
    #pragma unroll
    for (int ml = 0; ml < 4; ++ml)
      #pragma unroll
      for (int kk = 0; kk < 2; ++kk)
        af1[ml][kk] = *(const bf16x8*)(&SMEM[bb + ((wr*8 + 4 + ml)*2 + kk)*512 + rbase]);
    if (pf) STAGE2_(nbb, k0 + 64, 2);
    asm volatile("s_waitcnt lgkmcnt(0)" ::: "memory");
    __builtin_amdgcn_sched_barrier(0);
    __builtin_amdgcn_s_setprio(1);
    #pragma unroll
    for (int ml = 0; ml < 4; ++ml)
      #pragma unroll
      for (int n = 0; n < 2; ++n) {
        acc[4+ml][n] = __builtin_amdgcn_mfma_f32_16x16x32_bf16(af1[ml][0], bfr[n][0], acc[4+ml][n], 0, 0, 0);
        acc[4+ml][n] = __builtin_amdgcn_mfma_f32_16x16x32_bf16(af1[ml][1], bfr[n][1], acc[4+ml][n], 0, 0, 0);
      }
    __builtin_amdgcn_s_setprio(0);
    __builtin_amdgcn_s_barrier();
    // ---------------- P4 ----------------
    if (pf) STAGE2_(nbb, k0 + 64, 3);
    __builtin_amdgcn_s_setprio(1);
    #pragma unroll
    for (int ml = 0; ml < 4; ++ml)
      #pragma unroll
      for (int n = 2; n < 4; ++n) {
        acc[4+ml][n] = __builtin_amdgcn_mfma_f32_16x16x32_bf16(af1[ml][0], bfr[n][0], acc[4+ml][n], 0, 0, 0);
        acc[4+ml][n] = __builtin_amdgcn_mfma_f32_16x16x32_bf16(af1[ml][1], bfr[n][1], acc[4+ml][n], 0, 0, 0);
      }
    __builtin_amdgcn_s_setprio(0);
    __builtin_amdgcn_s_barrier();
  }
#undef STAGE2_

  const int seg = (EP == 5) ? (bcol / 768) : 0;     // block-uniform (256|768 grid)
  unsigned short* qkvp = nullptr;
  if (EP == 5)
    qkvp = (seg == 0) ? (unsigned short*)outv
         : (seg == 1) ? (unsigned short*)residv : (unsigned short*)aux;

  if (EP == 5 && seg == 2) {
    // v^T scatter store (per batch): vt[(b*768 + colLv)*1024 + token]
    #pragma unroll
    for (int n = 0; n < 4; ++n) {
      const int col = bcol + wc*64 + n*16 + lr;
      const float bv = bias[col];
      const int colLv = col - 1536;
      #pragma unroll
      for (int m = 0; m < 8; ++m) {
        const int row0 = brow + wr*128 + m*16 + lg*4;
        #pragma unroll
        for (int r2 = 0; r2 < 4; ++r2) {
          const int gr = row0 + r2;
          qkvp[(((size_t)(gr >> 10) * D_MODEL + colLv) << 10) + (gr & 1023)] =
              f2bf(acc[m][n][r2] + bv);
        }
      }
    }
  } else {
    // coalesced bounce: per-wave f32 tile [64 col][20 row] in SMEM (free now)
    float* Ep = (float*)SMEM + w * 1280;   // 5120 B per wave
    #pragma unroll
    for (int m = 0; m < 8; ++m) {
      #pragma unroll
      for (int n = 0; n < 4; ++n) {
        const int col = bcol + wc*64 + n*16 + lr;
        const float bv = bias[col];
        f32x4 st;
        #pragma unroll
        for (int r2 = 0; r2 < 4; ++r2) {
          float v = acc[m][n][r2] + bv;
          if (EP == 1 || EP == 3) v = gelu_f(v);
          st[r2] = v;
        }
        *(f32x4*)(Ep + (n*16 + lr) * 20 + lg*4) = st;
      }
      #pragma unroll
      for (int i2 = 0; i2 < 2; ++i2) {
        const int rowL = i2*8 + (lane >> 3);
        const int colL = (lane & 7) * 8;
        const int grow = brow + wr*128 + m*16 + rowL;
        const int gcol = bcol + wc*64 + colL;
        float v[8];
        #pragma unroll
        for (int j = 0; j < 8; ++j) v[j] = Ep[(colL + j) * 20 + rowL];
        const size_t o = (size_t)grow * N + gcol;
        if (EP == 3) {
          const bf16x8 rv = *(const bf16x8*)((const __bf16*)residv + o);
          float* op = (float*)outv + o;
          float4 o0, o1;
          o0.x = v[0] + (float)rv[0]; o0.y = v[1] + (float)rv[1];
          o0.z = v[2] + (float)rv[2]; o0.w = v[3] + (float)rv[3];
          o1.x = v[4] + (float)rv[4]; o1.y = v[5] + (float)rv[5];
          o1.z = v[6] + (float)rv[6]; o1.w = v[7] + (float)rv[7];
          *(float4*)op = o0; *(float4*)(op + 4) = o1;
        } else if (EP == 2) {
          const float* rp = (const float*)residv + o;
          const float4 r0 = *(const float4*)rp, r1 = *(const float4*)(rp + 4);
          bf16x8 ov;
          ov[0] = (__bf16)(v[0] + r0.x); ov[1] = (__bf16)(v[1] + r0.y);
          ov[2] = (__bf16)(v[2] + r0.z); ov[3] = (__bf16)(v[3] + r0.w);
          ov[4] = (__bf16)(v[4] + r1.x); ov[5] = (__bf16)(v[5] + r1.y);
          ov[6] = (__bf16)(v[6] + r1.z); ov[7] = (__bf16)(v[7] + r1.w);
          *(bf16x8*)((__bf16*)outv + o) = ov;
        } else if (EP == 5) {          // q/k segment, 768-wide dest
          bf16x8 ov;
          #pragma unroll
          for (int j = 0; j < 8; ++j) ov[j] = (__bf16)v[j];
          *(bf16x8*)((__bf16*)qkvp + (size_t)grow * 768 + (gcol - seg * 768)) = ov;
        } else {                       // EP 0 / 1
          bf16x8 ov;
          #pragma unroll
          for (int j = 0; j < 8; ++j) ov[j] = (__bf16)v[j];
          *(bf16x8*)((__bf16*)outv + o) = ov;
        }
      }
    }
  }
}

// ---------------- flash attention: 768 blocks, XCD-sequential bh -----------
__global__ __launch_bounds__(512) void attn_k(
    const unsigned short* qu, const unsigned short* __restrict__ ku,
    const unsigned short* __restrict__ vtu, unsigned short* attn) {
  __shared__ __align__(16) __bf16 Kl[64][72];
  __shared__ __align__(16) __bf16 Vl[64][72];
  __shared__ __align__(16) __bf16 Pl[8][16][72];
  const __bf16* qg  = (const __bf16*)qu;
  const __bf16* kg  = (const __bf16*)ku;
  const __bf16* vtg = (const __bf16*)vtu;
  const int bid = blockIdx.x;
  const int xcd = bid & 7, idx = bid >> 3;
  const int bh = xcd * 24 + (idx >> 2);
  const int b = bh / 12, h = bh % 12;
  const int q0 = (idx & 3) * 256;
  const int tid = threadIdx.x, lane = tid & 63, w = tid >> 6;
  const int lr = lane & 15, lg = lane >> 4;
  const float scale = 0.03608439182435161f; // 1/sqrt(768)

  bf16x8 qa[2][2];
  #pragma unroll
  for (int g = 0; g < 2; ++g) {
    const int qrow = b * T_SEQ + q0 + w * 32 + g * 16 + lr;
    const __bf16* qp = qg + (size_t)qrow * D_MODEL + h * 64 + lg * 8;
    qa[g][0] = *(const bf16x8*)(qp);
    qa[g][1] = *(const bf16x8*)(qp + 32);
  }

  const __bf16* kb = kg  + (size_t)b * T_SEQ * D_MODEL + h * 64;
  const __bf16* vb = vtg + ((size_t)b * D_MODEL + h * 64) * T_SEQ;

  f32x4 o[2][4];
  float m_run[2] = {-1e30f, -1e30f}, l_run[2] = {0.f, 0.f};
  #pragma unroll
  for (int g = 0; g < 2; ++g)
    #pragma unroll
    for (int m = 0; m < 4; ++m) o[g][m] = (f32x4){0.f, 0.f, 0.f, 0.f};

  for (int kv0 = 0; kv0 < T_SEQ; kv0 += 64) {
    __syncthreads();
    {
      const int r = tid >> 3, c = (tid & 7) << 3;
      *(bf16x8*)(&Kl[r][c]) = *(const bf16x8*)(kb + (size_t)(kv0 + r) * D_MODEL + c);
      *(bf16x8*)(&Vl[r][c]) = *(const bf16x8*)(vb + (size_t)r * T_SEQ + kv0 + c);
    }
    __syncthreads();

    #pragma unroll
    for (int g = 0; g < 2; ++g) {
      f32x4 s[4];
      __builtin_amdgcn_s_setprio(1);
      #pragma unroll
      for (int m = 0; m < 4; ++m) {
        s[m] = (f32x4){0.f, 0.f, 0.f, 0.f};
        const bf16x8 kf0 = *(const bf16x8*)(&Kl[m*16 + lr][lg*8]);
        const bf16x8 kf1 = *(const bf16x8*)(&Kl[m*16 + lr][32 + lg*8]);
        s[m] = __builtin_amdgcn_mfma_f32_16x16x32_bf16(kf0, qa[g][0], s[m], 0, 0, 0);
        s[m] = __builtin_amdgcn_mfma_f32_16x16x32_bf16(kf1, qa[g][1], s[m], 0, 0, 0);
      }
      __builtin_amdgcn_s_setprio(0);
      float sv[4][4], tm = -1e30f;
      #pragma unroll
      for (int m = 0; m < 4; ++m)
        #pragma unroll
        for (int r = 0; r < 4; ++r) {
          sv[m][r] = s[m][r] * scale;
          tm = fmaxf(tm, sv[m][r]);
        }
      tm = fmaxf(tm, __shfl_xor(tm, 16));
      tm = fmaxf(tm, __shfl_xor(tm, 32));
      const float mn = fmaxf(m_run[g], tm);
      const float sc = __expf(m_run[g] - mn);
      float ts = 0.f;
      bf16x4 pk[4];
      #pragma unroll
      for (int m = 0; m < 4; ++m)
        #pragma unroll
        for (int r = 0; r < 4; ++r) {
          const float pp = __expf(sv[m][r] - mn);
          ts += pp;
          pk[m][r] = (__bf16)pp;
        }
      ts += __shfl_xor(ts, 16);
      ts += __shfl_xor(ts, 32);
      l_run[g] = l_run[g] * sc + ts;
      m_run[g] = mn;
      #pragma unroll
      for (int m = 0; m < 4; ++m)
        #pragma unroll
        for (int r = 0; r < 4; ++r) o[g][m][r] *= sc;
      #pragma unroll
      for (int m = 0; m < 4; ++m)
        *(bf16x4*)(&Pl[w][lr][16*m + 4*lg]) = pk[m];
      const bf16x8 pf0 = *(const bf16x8*)(&Pl[w][lr][lg*8]);
      const bf16x8 pf1 = *(const bf16x8*)(&Pl[w][lr][32 + lg*8]);
      __builtin_amdgcn_s_setprio(1);
      #pragma unroll
      for (int m = 0; m < 4; ++m) {
        const bf16x8 vf0 = *(const bf16x8*)(&Vl[m*16 + lr][lg*8]);
        const bf16x8 vf1 = *(const bf16x8*)(&Vl[m*16 + lr][32 + lg*8]);
        o[g][m] = __builtin_amdgcn_mfma_f32_16x16x32_bf16(vf0, pf0, o[g][m], 0, 0, 0);
        o[g][m] = __builtin_amdgcn_mfma_f32_16x16x32_bf16(vf1, pf1, o[g][m], 0, 0, 0);
      }
      __builtin_amdgcn_s_setprio(0);
    }
  }

  #pragma unroll
  for (int g = 0; g < 2; ++g) {
    const float inv = 1.0f / l_run[g];
    const int qrow = b * T_SEQ + q0 + w * 32 + g * 16 + lr;
    unsigned short* op = attn + (size_t)qrow * D_MODEL + h * 64;
    #pragma unroll
    for (int m = 0; m < 4; ++m) {
      bf16x4 ov;
      #pragma unroll
      for (int r = 0; r < 4; ++r) ov[r] = (__bf16)(o[g][m][r] * inv);
      *(bf16x4*)(op + 16*m + 4*lg) = ov;
    }
  }
}

// ---------------------------------------------------------------------------
extern "C" void kernel_launch(void* const* d_in, const int* in_sizes, int n_in,
                              void* d_out, int out_size, void* d_ws, size_t ws_size,
                              hipStream_t stream) {
  const float* x   = (const float*)d_in[0];
  const float* Wq  = (const float*)d_in[1];
  const float* bq  = (const float*)d_in[2];
  const float* Wk  = (const float*)d_in[3];
  const float* bk  = (const float*)d_in[4];
  const float* Wv  = (const float*)d_in[5];
  const float* bv  = (const float*)d_in[6];
  const float* Wo  = (const float*)d_in[7];
  const float* bo  = (const float*)d_in[8];
  const float* g1  = (const float*)d_in[9];
  const float* bt1 = (const float*)d_in[10];
  const float* g2  = (const float*)d_in[11];
  const float* bt2 = (const float*)d_in[12];
  const float* W1  = (const float*)d_in[13];
  const float* bb1 = (const float*)d_in[14];
  const float* W2  = (const float*)d_in[15];
  const float* bb2 = (const float*)d_in[16];

  const size_t SZ = (size_t)M_ROWS * D_MODEL * 2;   // 25,165,824
  char* wp = (char*)d_ws;
  unsigned short* wqkvT = (unsigned short*)wp; wp += (size_t)2304 * 768 * 2;
  unsigned short* woT   = (unsigned short*)wp; wp += (size_t)768 * 768 * 2;
  unsigned short* w1T   = (unsigned short*)wp; wp += (size_t)768 * 3072 * 2;
  unsigned short* w2T   = (unsigned short*)wp; wp += (size_t)768 * 3072 * 2;
  float*          bqkv  = (float*)wp;          wp += ((size_t)2304 * 4 + 255) & ~(size_t)255;
  unsigned short* kbuf  = (unsigned short*)wp; wp += SZ;   // k -> res2
  unsigned short* vtb   = (unsigned short*)wp;             // vT -> hid
  unsigned short* res2  = kbuf;
  unsigned short* hid   = vtb;
  const size_t avail = ws_size - (size_t)(wp - (char*)d_ws);
  const int nch = (avail >= (size_t)M_ROWS * MLP_DIM * 2) ? 1
                : (avail >= (size_t)(M_ROWS / 2) * MLP_DIM * 2) ? 2 : 4;

  unsigned short* qd = (unsigned short*)d_out;             // bf16 lo half
  unsigned short* h1 = qd + (size_t)M_ROWS * D_MODEL;      // bf16 hi half
  unsigned short* h2 = h1;

  const dim3 tb(32, 8, 1);
  wtr_k<<<dim3(24, 24), tb, 0, stream>>>(Wq, wqkvT, 768, 768);
  wtr_k<<<dim3(24, 24), tb, 0, stream>>>(Wk, wqkvT + (size_t)768 * 768, 768, 768);
  wtr_k<<<dim3(24, 24), tb, 0, stream>>>(Wv, wqkvT + (size_t)1536 * 768, 768, 768);
  wtr_k<<<dim3(24, 24), tb, 0, stream>>>(Wo, woT, 768, 768);
  wtr_k<<<dim3(96, 24), tb, 0, stream>>>(W1, w1T, 768, 3072);
  wtr_k<<<dim3(24, 96), tb, 0, stream>>>(W2, w2T, 3072, 768);
  bcat_k<<<3, 256, 0, stream>>>(bq, bk, bv, bqkv);

  ln_k<1><<<M_ROWS, 256, 0, stream>>>(x, g1, bt1, h1);

  gemm_k<5><<<dim3(64, 9), 512, 0, stream>>>(h1, wqkvT, bqkv, qd, kbuf, vtb,
                                             M_ROWS, 2304, 768, 9);

  attn_k<<<dim3(768), 512, 0, stream>>>(qd, kbuf, vtb, qd);

  gemm_k<2><<<dim3(64, 3), 512, 0, stream>>>(qd, woT, bo, res2, x, nullptr,
                                             M_ROWS, 768, 768, 3);

  ln_k<0><<<M_ROWS, 256, 0, stream>>>(res2, g2, bt2, h2);

  const int CH = M_ROWS / nch;
  for (int c = 0; c < nch; ++c) {
    const size_t ro = (size_t)c * CH;
    gemm_k<1><<<dim3(CH / 256, 12), 512, 0, stream>>>(h2 + ro * 768, w1T, bb1,
        hid, nullptr, nullptr, CH, 3072, 768, 6);
    gemm_k<3><<<dim3(CH / 256, 3), 512, 0, stream>>>(hid, w2T, bb2,
        (float*)d_out + ro * 768, res2 + ro * 768, nullptr, CH, 768, 3072, 3);
  }
}